// Round 11
// baseline (558.391 us; speedup 1.0000x reference)
//
#include <hip/hip_runtime.h>
#include <stdint.h>

#define S_LEN 2048
#define D_MODEL 1024
#define N_HEAD 16
#define D_HEAD 64
#define N_BATCH 2
#define M_TOK (N_BATCH * S_LEN)  // 4096

typedef unsigned short u16;
typedef unsigned int u32;
typedef unsigned long long u64;
typedef __attribute__((ext_vector_type(8))) short bf16x8;
typedef __attribute__((ext_vector_type(4))) short s16x4;
typedef __attribute__((ext_vector_type(4))) float f32x4;
typedef __attribute__((ext_vector_type(4))) unsigned short u16x4;

#define MFMA16(a, b, c) __builtin_amdgcn_mfma_f32_16x16x32_bf16((a), (b), (c), 0, 0, 0)

#if defined(__has_builtin)
#if __has_builtin(__builtin_amdgcn_mfma_f32_16x16x16bf16_1k)
#define HAVE_MFMA_16x16x16 1
#define MFMA_PV(a, b, c) __builtin_amdgcn_mfma_f32_16x16x16bf16_1k((a), (b), (c), 0, 0, 0)
#endif
#endif

#define WAITCNT(n) asm volatile("s_waitcnt vmcnt(" #n ")" ::: "memory")
#define BAR() __builtin_amdgcn_s_barrier()

__device__ __forceinline__ u16 f2bf(float f) {
  unsigned int u = __float_as_uint(f);
  u = (u + 0x7FFFu + ((u >> 16) & 1u)) >> 16;
  return (u16)u;
}

__device__ __forceinline__ void gload_lds16(const u16* g, u16* l) {
  __builtin_amdgcn_global_load_lds((const __attribute__((address_space(1))) void*)g,
                                   (__attribute__((address_space(3))) void*)l, 16, 0, 0);
}

// ---------------- fp32 -> bf16 convert, all 7 tensors in one launch ----------------
#define N4BIG (M_TOK * D_MODEL / 4)     // 1048576
#define N4W (D_MODEL * D_MODEL / 4)     // 262144
__global__ __launch_bounds__(256) void cvt7_kernel(
    const float* __restrict__ sk, const float* __restrict__ sv, const float* __restrict__ sq,
    const float* __restrict__ swq, const float* __restrict__ swk, const float* __restrict__ swv,
    const float* __restrict__ swo, u16* __restrict__ dk, u16* __restrict__ dv, u16* __restrict__ dq,
    u16* __restrict__ dwq, u16* __restrict__ dwk, u16* __restrict__ dwv, u16* __restrict__ dwo) {
  const float* s;
  u16* d;
  int n4;
  switch (blockIdx.y) {
    case 0: s = sk; d = dk; n4 = N4BIG; break;
    case 1: s = sv; d = dv; n4 = N4BIG; break;
    case 2: s = sq; d = dq; n4 = N4BIG; break;
    case 3: s = swq; d = dwq; n4 = N4W; break;
    case 4: s = swk; d = dwk; n4 = N4W; break;
    case 5: s = swv; d = dwv; n4 = N4W; break;
    default: s = swo; d = dwo; n4 = N4W; break;
  }
  int i = blockIdx.x * blockDim.x + threadIdx.x;
  int stride = gridDim.x * blockDim.x;
  for (; i < n4; i += stride) {
    float4 v = ((const float4*)s)[i];
    u16x4 o = {f2bf(v.x), f2bf(v.y), f2bf(v.z), f2bf(v.w)};
    ((u16x4*)d)[i] = o;
  }
}

// ---------------- mask bit-pack: int32[4096][2048] -> u64[4096][32] -----------------
__global__ __launch_bounds__(256) void pack_mask(const int* __restrict__ mask,
                                                 u64* __restrict__ packed) {
  int wid = (blockIdx.x * blockDim.x + threadIdx.x) >> 6;
  int lane = threadIdx.x & 63;
  int nw = (gridDim.x * blockDim.x) >> 6;
  const int NW64 = M_TOK * (S_LEN / 64);  // 131072
  for (int widx = wid; widx < NW64; widx += nw) {
    int m = mask[(size_t)widx * 64 + lane];
    u64 bits = __ballot(m != 0);
    if (lane == 0) packed[widx] = bits;
  }
}

// ---------------- GEMM body: C[M,N] = A[M,K]@Bw[N,K]^T, +bias, *scale ----------------
__device__ __forceinline__ void gemm_body(const u16* __restrict__ A, const u16* __restrict__ Bw,
                                          const float* __restrict__ bias, void* __restrict__ Cout,
                                          float scale, int outmode) {
  __shared__ u16 As[128 * 32];
  __shared__ u16 Bs[128 * 32];
  const int K = D_MODEL, N = D_MODEL;
  int tid = threadIdx.x;
  int w = tid >> 6, lane = tid & 63, lg = lane >> 4, lr = lane & 15;
  int m0 = blockIdx.x * 128, n0 = blockIdx.y * 128;
  int wr = w >> 1, wc = w & 1;
  f32x4 acc[4][4] = {};
  int r0 = tid >> 2;
  int r1 = 64 + (tid >> 2);
  int kk0 = (tid & 3) * 8;
  for (int kb = 0; kb < K; kb += 32) {
    gload_lds16(A + (size_t)(m0 + r0) * K + kb + kk0, As + w * 512);
    gload_lds16(A + (size_t)(m0 + r1) * K + kb + kk0, As + 2048 + w * 512);
    gload_lds16(Bw + (size_t)(n0 + r0) * K + kb + kk0, Bs + w * 512);
    gload_lds16(Bw + (size_t)(n0 + r1) * K + kb + kk0, Bs + 2048 + w * 512);
    __syncthreads();
    bf16x8 af[4], bfr[4];
#pragma unroll
    for (int i = 0; i < 4; i++)
      af[i] = *(const bf16x8*)(As + (wr * 64 + i * 16 + lr) * 32 + lg * 8);
#pragma unroll
    for (int i = 0; i < 4; i++)
      bfr[i] = *(const bf16x8*)(Bs + (wc * 64 + i * 16 + lr) * 32 + lg * 8);
#pragma unroll
    for (int mi = 0; mi < 4; mi++)
#pragma unroll
      for (int ni = 0; ni < 4; ni++)
        acc[mi][ni] = MFMA16(af[mi], bfr[ni], acc[mi][ni]);
    __syncthreads();
  }
#pragma unroll
  for (int mi = 0; mi < 4; mi++)
#pragma unroll
    for (int ni = 0; ni < 4; ni++) {
      int col = n0 + wc * 64 + ni * 16 + lr;
      float bv = bias[col];
      if (outmode == 2) {
        int row0 = m0 + wr * 64 + mi * 16 + lg * 4;
        int bb = row0 >> 11, ss = row0 & (S_LEN - 1);
        u16x4 pk;
#pragma unroll
        for (int r = 0; r < 4; r++) pk[r] = f2bf((acc[mi][ni][r] + bv) * scale);
        *(u16x4*)((u16*)Cout + ((size_t)((bb * N_HEAD + (col >> 6)) * D_HEAD + (col & 63)) * S_LEN + ss)) = pk;
      } else {
#pragma unroll
        for (int r = 0; r < 4; r++) {
          int row = m0 + wr * 64 + mi * 16 + lg * 4 + r;
          float v = (acc[mi][ni][r] + bv) * scale;
          if (outmode == 1)
            ((float*)Cout)[(size_t)row * N + col] = v;
          else
            ((u16*)Cout)[(size_t)row * N + col] = f2bf(v);
        }
      }
    }
}

// Q scale folds 1/sqrt(64) * log2(e) so attention uses exp2 directly.
#define QSCALE 0.18033688011112042f

__global__ __launch_bounds__(256) void proj3_kernel(
    const u16* __restrict__ kbf, const u16* __restrict__ vbf, const u16* __restrict__ qbf,
    const u16* __restrict__ wkb, const u16* __restrict__ wvb, const u16* __restrict__ wqb,
    const float* __restrict__ bk, const float* __restrict__ bv, const float* __restrict__ bq,
    u16* __restrict__ kup, u16* __restrict__ vtg, u16* __restrict__ qup) {
  int z = blockIdx.z;
  if (z == 0)
    gemm_body(kbf, wkb, bk, kup, 1.0f, 0);
  else if (z == 1)
    gemm_body(vbf, wvb, bv, vtg, 1.0f, 2);
  else
    gemm_body(qbf, wqb, bq, qup, QSCALE, 0);
}

__global__ __launch_bounds__(256) void gemm_out_kernel(const u16* __restrict__ A,
                                                       const u16* __restrict__ Bw,
                                                       const float* __restrict__ bias,
                                                       float* __restrict__ C) {
  gemm_body(A, Bw, bias, C, 1.0f, 1);
}

// ---------------- attention pass 0: partial row sums, k-split x2 --------------------
// grid = 2048 flat (XCD swizzled): (b, h, qb 0..31, khalf). 256 thr = 4 waves; wave w
// owns q-rows [qb*64 + 16w, +16) over k in [khalf*1024, +1024) (16 tiles of 64).
__global__ __launch_bounds__(256, 8) void attn_p0(const u16* __restrict__ Qup,
                                                  const u16* __restrict__ Kup,
                                                  const u32* __restrict__ mpack,
                                                  float* __restrict__ lsums) {
  __shared__ u16 kbuf[2][64 * 64];
  int tid = threadIdx.x;
  int w = tid >> 6, lane = tid & 63, lg = lane >> 4, lr = lane & 15;
  int fb = blockIdx.x;
  int logical = (fb & 7) * 256 + (fb >> 3);
  int khalf = logical & 1;
  int qb = (logical >> 1) & 31;
  int h = (logical >> 6) & 15;
  int b = logical >> 10;
  int q0 = qb * 64;
  int q = q0 + w * 16 + lr;
  const float NEGV = -100000000.0f;

  bf16x8 qf0, qf1;
  {
    const u16* qrow = Qup + (size_t)(b * S_LEN + q) * D_MODEL + h * D_HEAD;
    qf0 = *(const bf16x8*)(qrow + lg * 8);
    qf1 = *(const bf16x8*)(qrow + 32 + lg * 8);
  }
  const u16* Kb = Kup + (size_t)(b * S_LEN) * D_MODEL + h * D_HEAD;
  const u32* mrow = mpack + (size_t)(b * S_LEN + q) * (S_LEN / 32) + khalf * 32;

  int srow = tid >> 3;  // 0..31; second gload +32 (same &7)
  int schunk = (tid & 7) ^ (srow & 7);
  const u16* KgA = Kb + (size_t)(khalf * 1024 + srow) * D_MODEL + schunk * 8;
  const int sw = lr & 7;

#define STAGE_K0(bn, ktn)                                                   \
  do {                                                                      \
    const u16* _s = KgA + (size_t)(ktn) * 64 * D_MODEL;                     \
    gload_lds16(_s, &kbuf[bn][0] + w * 512);                                \
    gload_lds16(_s + (size_t)32 * D_MODEL, &kbuf[bn][2048] + w * 512);      \
  } while (0)

  float lsA = 0.f, lsB = 0.f;
#define P0_BODY(BN, MM)                                                     \
  {                                                                         \
    const u16* kc = &kbuf[BN][0];                                           \
    _Pragma("unroll") for (int t = 0; t < 4; t++) {                         \
      const u16* kr = kc + (t * 16 + lr) * 64;                              \
      bf16x8 k0 = *(const bf16x8*)(kr + ((lg ^ sw) << 3));                  \
      bf16x8 k1 = *(const bf16x8*)(kr + (((lg + 4) ^ sw) << 3));            \
      f32x4 a = {0.f, 0.f, 0.f, 0.f};                                       \
      a = MFMA16(k0, qf0, a);                                               \
      a = MFMA16(k1, qf1, a);                                               \
      u32 wbits = (t < 2) ? (MM).x : (MM).y;                                \
      _Pragma("unroll") for (int r = 0; r < 4; r++) {                       \
        int j = (t * 16 + lg * 4 + r) & 31;                                 \
        float s = ((wbits >> j) & 1u) ? NEGV : a[r];                        \
        if (r & 1) lsB += exp2f(s); else lsA += exp2f(s);                   \
      }                                                                     \
    }                                                                       \
  }

  uint2 mA, mB;
  mA = *(const uint2*)(mrow);
  STAGE_K0(0, 0);
  for (int it = 0; it < 7; it++) {
    int kt = it * 2;
    mB = *(const uint2*)(mrow + (kt + 1) * 2);
    STAGE_K0(1, kt + 1);
    WAITCNT(3);
    BAR();
    P0_BODY(0, mA);
    BAR();
    mA = *(const uint2*)(mrow + (kt + 2) * 2);
    STAGE_K0(0, kt + 2);
    WAITCNT(3);
    BAR();
    P0_BODY(1, mB);
    BAR();
  }
  mB = *(const uint2*)(mrow + 15 * 2);
  STAGE_K0(1, 15);
  WAITCNT(3);
  BAR();
  P0_BODY(0, mA);
  BAR();
  WAITCNT(0);
  BAR();
  P0_BODY(1, mB);

  float lsum = lsA + lsB;
  lsum += __shfl_xor(lsum, 16);
  lsum += __shfl_xor(lsum, 32);
  if (lg == 0) lsums[(size_t)khalf * 65536 + (size_t)(b * N_HEAD + h) * S_LEN + q] = lsum;
#undef STAGE_K0
#undef P0_BODY
}

// ---------------- attention pass 1: 4-wave blocks, k-split x2, high occupancy -------
// grid = 2048 flat (XCD swizzled): (b, h, qb 0..31, khalf). 256 thr = 4 waves; wave w
// owns q-rows [qb*64+16w, +16) over k in [khalf*1024, +1024), 16 tiles of KVBLK=64.
// K dbuf in LDS (16KB, shared by 4 waves); V^T read per-lane from global (L2-hit,
// natural layout == 16x16x16 B-frag); P in-register -> PV; direct f32x4 attn stores.
// ctx partials (f32) go to ctx0 (khalf 0) / ctx1 (khalf 1); reduced later.
__global__ __launch_bounds__(256, 6) void attn_p1(
    const u16* __restrict__ Qup, const u16* __restrict__ Kup, const u16* __restrict__ Vt,
    const u32* __restrict__ mpack, const float* __restrict__ lsums,
    float* __restrict__ attn_out, float* __restrict__ ctx0, float* __restrict__ ctx1) {
  __shared__ u16 kbuf[2][64 * 64];  // 16 KB
#if !defined(HAVE_MFMA_16x16x16)
  __shared__ u16 pbuf[4][16 * 64];  // 8 KB (fallback only)
#endif
  int tid = threadIdx.x;
  int w = tid >> 6, lane = tid & 63, lg = lane >> 4, lr = lane & 15;
  int fb = blockIdx.x;
  int logical = (fb & 7) * 256 + (fb >> 3);
  int khalf = logical & 1;
  int qb = (logical >> 1) & 31;
  int h = (logical >> 6) & 15;
  int b = logical >> 10;
  int q0 = qb * 64;
  int q = q0 + w * 16 + lr;
  const float NEGV = -100000000.0f;

  bf16x8 qf0, qf1;
  {
    const u16* qrow = Qup + (size_t)(b * S_LEN + q) * D_MODEL + h * D_HEAD;
    qf0 = *(const bf16x8*)(qrow + lg * 8);
    qf1 = *(const bf16x8*)(qrow + 32 + lg * 8);
  }
  const u16* Kb = Kup + (size_t)(b * S_LEN) * D_MODEL + h * D_HEAD;
  const u16* Vb = Vt + (size_t)(b * N_HEAD + h) * D_HEAD * S_LEN + khalf * 1024;
  const u32* mrow = mpack + (size_t)(b * S_LEN + q) * (S_LEN / 32) + khalf * 32;
  float* attn_b = attn_out + ((size_t)(b * N_HEAD + h) * S_LEN + q) * S_LEN + khalf * 1024;

  float il2;
  {
    size_t idx = (size_t)(b * N_HEAD + h) * S_LEN + q;
    float tot = lsums[idx] + lsums[65536 + idx];
    il2 = tot > 0.f ? -__log2f(tot) : 0.f;
  }

  int srow = tid >> 3;
  int schunk = (tid & 7) ^ (srow & 7);
  const u16* KgA = Kb + (size_t)(khalf * 1024 + srow) * D_MODEL + schunk * 8;
  const int sw = lr & 7;

#define STAGE_K1(bn, ktn)                                                   \
  do {                                                                      \
    const u16* _s = KgA + (size_t)(ktn) * 64 * D_MODEL;                     \
    gload_lds16(_s, &kbuf[bn][0] + w * 512);                                \
    gload_lds16(_s + (size_t)32 * D_MODEL, &kbuf[bn][2048] + w * 512);      \
  } while (0)

  f32x4 ctxacc[4] = {};

#if defined(HAVE_MFMA_16x16x16)
#define P1_BODY(BN, MM, KT)                                                 \
  {                                                                         \
    const u16* kc = &kbuf[BN][0];                                           \
    const u16* vg = Vb + (KT) * 64;                                         \
    _Pragma("unroll") for (int t = 0; t < 4; t++) {                         \
      const u16* kr = kc + (t * 16 + lr) * 64;                              \
      bf16x8 k0 = *(const bf16x8*)(kr + ((lg ^ sw) << 3));                  \
      bf16x8 k1 = *(const bf16x8*)(kr + (((lg + 4) ^ sw) << 3));            \
      f32x4 a = {0.f, 0.f, 0.f, 0.f};                                       \
      a = MFMA16(k0, qf0, a);                                               \
      a = MFMA16(k1, qf1, a);                                               \
      u32 wbits = (t < 2) ? (MM).x : (MM).y;                                \
      f32x4 p;                                                              \
      u16x4 pb;                                                             \
      _Pragma("unroll") for (int r = 0; r < 4; r++) {                       \
        int j = (t * 16 + lg * 4 + r) & 31;                                 \
        float s = ((wbits >> j) & 1u) ? NEGV : (a[r] + il2);                \
        float pv = exp2f(s);                                                \
        p[r] = pv;                                                          \
        pb[r] = f2bf(pv);                                                   \
      }                                                                     \
      *(f32x4*)(attn_b + (KT) * 64 + t * 16 + lg * 4) = p;                  \
      s16x4 ap = {(short)pb[0], (short)pb[1], (short)pb[2], (short)pb[3]};  \
      _Pragma("unroll") for (int d = 0; d < 4; d++) {                       \
        s16x4 vf = *(const s16x4*)(vg + (size_t)(d * 16 + lr) * S_LEN +     \
                                   t * 16 + lg * 4);                        \
        ctxacc[d] = MFMA_PV(ap, vf, ctxacc[d]);                             \
      }                                                                     \
    }                                                                       \
  }
#else
#define P1_BODY(BN, MM, KT)                                                 \
  {                                                                         \
    const u16* kc = &kbuf[BN][0];                                           \
    const u16* vg = Vb + (KT) * 64;                                         \
    u16* pw = &pbuf[w][0];                                                  \
    _Pragma("unroll") for (int t = 0; t < 4; t++) {                         \
      const u16* kr = kc + (t * 16 + lr) * 64;                              \
      bf16x8 k0 = *(const bf16x8*)(kr + ((lg ^ sw) << 3));                  \
      bf16x8 k1 = *(const bf16x8*)(kr + (((lg + 4) ^ sw) << 3));            \
      f32x4 a = {0.f, 0.f, 0.f, 0.f};                                       \
      a = MFMA16(k0, qf0, a);                                               \
      a = MFMA16(k1, qf1, a);                                               \
      u32 wbits = (t < 2) ? (MM).x : (MM).y;                                \
      f32x4 p;                                                              \
      u16x4 pb;                                                             \
      _Pragma("unroll") for (int r = 0; r < 4; r++) {                       \
        int j = (t * 16 + lg * 4 + r) & 31;                                 \
        float s = ((wbits >> j) & 1u) ? NEGV : (a[r] + il2);                \
        float pv = exp2f(s);                                                \
        p[r] = pv;                                                          \
        pb[r] = f2bf(pv);                                                   \
      }                                                                     \
      *(f32x4*)(attn_b + (KT) * 64 + t * 16 + lg * 4) = p;                  \
      *(u16x4*)(pw + lr * 64 + (((t * 2 + (lg >> 1)) ^ sw) << 3) +          \
                ((lg & 1) << 2)) = pb;                                      \
    }                                                                       \
    bf16x8 pa0 = *(const bf16x8*)(pw + lr * 64 + ((lg ^ sw) << 3));         \
    bf16x8 pa1 = *(const bf16x8*)(pw + lr * 64 + (((lg + 4) ^ sw) << 3));   \
    _Pragma("unroll") for (int d = 0; d < 4; d++) {                         \
      const u16* vr = vg + (size_t)(d * 16 + lr) * S_LEN;                   \
      bf16x8 v0 = *(const bf16x8*)(vr + lg * 8);                            \
      bf16x8 v1 = *(const bf16x8*)(vr + 32 + lg * 8);                       \
      ctxacc[d] = MFMA16(pa0, v0, ctxacc[d]);                               \
      ctxacc[d] = MFMA16(pa1, v1, ctxacc[d]);                               \
    }                                                                       \
  }
#endif

  uint2 mA, mB;
  mA = *(const uint2*)(mrow);
  STAGE_K1(0, 0);
  for (int it = 0; it < 7; it++) {
    int kt = it * 2;
    mB = *(const uint2*)(mrow + (kt + 1) * 2);
    STAGE_K1(1, kt + 1);
    WAITCNT(3);  // leave {mask kt+1, stage kt+1 (2)}; retires stage kt + prev stores/V
    BAR();
    P1_BODY(0, mA, kt);
    BAR();
    mA = *(const uint2*)(mrow + (kt + 2) * 2);
    STAGE_K1(0, kt + 2);
    WAITCNT(3);
    BAR();
    P1_BODY(1, mB, kt + 1);
    BAR();
  }
  mB = *(const uint2*)(mrow + 15 * 2);
  STAGE_K1(1, 15);
  WAITCNT(3);
  BAR();
  P1_BODY(0, mA, 14);
  BAR();
  WAITCNT(0);
  BAR();
  P1_BODY(1, mB, 15);

  // ctx partial out (f32): khalf 0 -> ctx0 (ws), khalf 1 -> ctx1 (d_out out-region)
  float* cdst = khalf ? ctx1 : ctx0;
#pragma unroll
  for (int d = 0; d < 4; d++)
#pragma unroll
    for (int r = 0; r < 4; r++) {
      int sq = q0 + w * 16 + lg * 4 + r;
      cdst[(size_t)(b * S_LEN + sq) * D_MODEL + h * D_HEAD + d * 16 + lr] = ctxacc[d][r];
    }
#undef STAGE_K1
#undef P1_BODY
}

// ---------------- ctx reduce: ctxb(bf16) = ctx0 + ctx1 ------------------------------
__global__ __launch_bounds__(256) void ctx_reduce(const float* __restrict__ c0,
                                                  const float* __restrict__ c1,
                                                  u16* __restrict__ dst) {
  int i = blockIdx.x * 256 + threadIdx.x;  // over 1M float4 groups
  f32x4 a = ((const f32x4*)c0)[i];
  f32x4 bv = ((const f32x4*)c1)[i];
  u16x4 o = {f2bf(a[0] + bv[0]), f2bf(a[1] + bv[1]), f2bf(a[2] + bv[2]), f2bf(a[3] + bv[3])};
  ((u16x4*)dst)[i] = o;
}

// ---------------- workspace layout (u16 units) ----------------
// Phase 1 (cvt/proj): kbf@0, vbf@4194304, qbf@8388608, weights@12582912.., qup/kup/vtg.
// Phase 2 (attn): ctx0 f32 16MB @0 (over dead kbf+vbf); mask u64 1MB @O_CTX;
//                 lsums f32 512KB @O_CTX+524288; ctx1 f32 = d_out out-region.
// Phase 3: ctxb bf16 8MB @O_CTX (overwrites mask+lsums after use).
#define O_KBF 0u
#define O_VBF 4194304u
#define O_QBF 8388608u
#define O_WQ 12582912u
#define O_WK 13631488u
#define O_WV 14680064u
#define O_WO 15728640u
#define O_QUP 16777216u
#define O_KUP 20971520u
#define O_VUP 25165824u
#define O_CTX 29360128u
// total = 33554432 u16 = 64 MiB

extern "C" void kernel_launch(void* const* d_in, const int* in_sizes, int n_in,
                              void* d_out, int out_size, void* d_ws, size_t ws_size,
                              hipStream_t stream) {
  const float* key = (const float*)d_in[0];
  const float* value = (const float*)d_in[1];
  const float* query = (const float*)d_in[2];
  const int* mask = (const int*)d_in[3];
  const float* Wq = (const float*)d_in[4];
  const float* bq = (const float*)d_in[5];
  const float* Wk = (const float*)d_in[6];
  const float* bk = (const float*)d_in[7];
  const float* Wv = (const float*)d_in[8];
  const float* bv = (const float*)d_in[9];
  const float* Wo = (const float*)d_in[10];
  const float* bo = (const float*)d_in[11];

  u16* ws = (u16*)d_ws;
  u16* kbf = ws + O_KBF;
  u16* vbf = ws + O_VBF;
  u16* qbf = ws + O_QBF;
  u16* wqb = ws + O_WQ;
  u16* wkb = ws + O_WK;
  u16* wvb = ws + O_WV;
  u16* wob = ws + O_WO;
  u16* qup = ws + O_QUP;
  u16* kup = ws + O_KUP;
  u16* vtg = ws + O_VUP;
  u16* ctxb = ws + O_CTX;
  u64* maskp = (u64*)(ws + O_CTX);                 // 1 MB
  float* lsums = (float*)(ws + O_CTX + 524288);    // 512 KB
  float* ctx0 = (float*)(ws + O_KBF);              // 16 MB over dead kbf+vbf

  float* out = (float*)d_out;
  float* attn = out + (size_t)N_BATCH * S_LEN * D_MODEL;
  float* ctx1 = out;  // out-region as f32 scratch; overwritten by gemm_out at the end

  cvt7_kernel<<<dim3(512, 7), 256, 0, stream>>>(key, value, query, Wq, Wk, Wv, Wo, kbf, vbf, qbf,
                                                wqb, wkb, wvb, wob);
  proj3_kernel<<<dim3(32, 8, 3), 256, 0, stream>>>(kbf, vbf, qbf, wkb, wvb, wqb, bk, bv, bq, kup,
                                                   vtg, qup);
  pack_mask<<<1024, 256, 0, stream>>>(mask, maskp);
  attn_p0<<<2048, 256, 0, stream>>>(qup, kup, (const u32*)maskp, lsums);
  attn_p1<<<2048, 256, 0, stream>>>(qup, kup, vtg, (const u32*)maskp, lsums, attn, ctx0, ctx1);
  ctx_reduce<<<4096, 256, 0, stream>>>(ctx0, ctx1, ctxb);
  gemm_out_kernel<<<dim3(32, 8), 256, 0, stream>>>(ctxb, wob, bo, out);
}

// Round 12
// 519.996 us; speedup vs baseline: 1.0738x; 1.0738x over previous
//
#include <hip/hip_runtime.h>
#include <stdint.h>

#define S_LEN 2048
#define D_MODEL 1024
#define N_HEAD 16
#define D_HEAD 64
#define N_BATCH 2
#define M_TOK (N_BATCH * S_LEN)  // 4096

typedef unsigned short u16;
typedef unsigned int u32;
typedef unsigned long long u64;
typedef __attribute__((ext_vector_type(8))) short bf16x8;
typedef __attribute__((ext_vector_type(4))) short s16x4;
typedef __attribute__((ext_vector_type(4))) float f32x4;
typedef __attribute__((ext_vector_type(4))) unsigned short u16x4;

#define MFMA16(a, b, c) __builtin_amdgcn_mfma_f32_16x16x32_bf16((a), (b), (c), 0, 0, 0)

#if defined(__has_builtin)
#if __has_builtin(__builtin_amdgcn_mfma_f32_16x16x16bf16_1k)
#define HAVE_MFMA_16x16x16 1
#define MFMA_PV(a, b, c) __builtin_amdgcn_mfma_f32_16x16x16bf16_1k((a), (b), (c), 0, 0, 0)
#endif
#endif

#define WAITCNT(n) asm volatile("s_waitcnt vmcnt(" #n ")" ::: "memory")
#define BAR() __builtin_amdgcn_s_barrier()

__device__ __forceinline__ u16 f2bf(float f) {
  unsigned int u = __float_as_uint(f);
  u = (u + 0x7FFFu + ((u >> 16) & 1u)) >> 16;
  return (u16)u;
}

__device__ __forceinline__ void gload_lds16(const u16* g, u16* l) {
  __builtin_amdgcn_global_load_lds((const __attribute__((address_space(1))) void*)g,
                                   (__attribute__((address_space(3))) void*)l, 16, 0, 0);
}

// ---------------- fp32 -> bf16 convert, all 7 tensors in one launch ----------------
#define N4BIG (M_TOK * D_MODEL / 4)     // 1048576
#define N4W (D_MODEL * D_MODEL / 4)     // 262144
__global__ __launch_bounds__(256) void cvt7_kernel(
    const float* __restrict__ sk, const float* __restrict__ sv, const float* __restrict__ sq,
    const float* __restrict__ swq, const float* __restrict__ swk, const float* __restrict__ swv,
    const float* __restrict__ swo, u16* __restrict__ dk, u16* __restrict__ dv, u16* __restrict__ dq,
    u16* __restrict__ dwq, u16* __restrict__ dwk, u16* __restrict__ dwv, u16* __restrict__ dwo) {
  const float* s;
  u16* d;
  int n4;
  switch (blockIdx.y) {
    case 0: s = sk; d = dk; n4 = N4BIG; break;
    case 1: s = sv; d = dv; n4 = N4BIG; break;
    case 2: s = sq; d = dq; n4 = N4BIG; break;
    case 3: s = swq; d = dwq; n4 = N4W; break;
    case 4: s = swk; d = dwk; n4 = N4W; break;
    case 5: s = swv; d = dwv; n4 = N4W; break;
    default: s = swo; d = dwo; n4 = N4W; break;
  }
  int i = blockIdx.x * blockDim.x + threadIdx.x;
  int stride = gridDim.x * blockDim.x;
  for (; i < n4; i += stride) {
    float4 v = ((const float4*)s)[i];
    u16x4 o = {f2bf(v.x), f2bf(v.y), f2bf(v.z), f2bf(v.w)};
    ((u16x4*)d)[i] = o;
  }
}

// ---------------- mask bit-pack: int32[4096][2048] -> u64[4096][32] -----------------
__global__ __launch_bounds__(256) void pack_mask(const int* __restrict__ mask,
                                                 u64* __restrict__ packed) {
  int wid = (blockIdx.x * blockDim.x + threadIdx.x) >> 6;
  int lane = threadIdx.x & 63;
  int nw = (gridDim.x * blockDim.x) >> 6;
  const int NW64 = M_TOK * (S_LEN / 64);  // 131072
  for (int widx = wid; widx < NW64; widx += nw) {
    int m = mask[(size_t)widx * 64 + lane];
    u64 bits = __ballot(m != 0);
    if (lane == 0) packed[widx] = bits;
  }
}

// ---------------- GEMM body: C[M,N] = A[M,K]@Bw[N,K]^T, +bias, *scale ----------------
__device__ __forceinline__ void gemm_body(const u16* __restrict__ A, const u16* __restrict__ Bw,
                                          const float* __restrict__ bias, void* __restrict__ Cout,
                                          float scale, int outmode) {
  __shared__ u16 As[128 * 32];
  __shared__ u16 Bs[128 * 32];
  const int K = D_MODEL, N = D_MODEL;
  int tid = threadIdx.x;
  int w = tid >> 6, lane = tid & 63, lg = lane >> 4, lr = lane & 15;
  int m0 = blockIdx.x * 128, n0 = blockIdx.y * 128;
  int wr = w >> 1, wc = w & 1;
  f32x4 acc[4][4] = {};
  int r0 = tid >> 2;
  int r1 = 64 + (tid >> 2);
  int kk0 = (tid & 3) * 8;
  for (int kb = 0; kb < K; kb += 32) {
    gload_lds16(A + (size_t)(m0 + r0) * K + kb + kk0, As + w * 512);
    gload_lds16(A + (size_t)(m0 + r1) * K + kb + kk0, As + 2048 + w * 512);
    gload_lds16(Bw + (size_t)(n0 + r0) * K + kb + kk0, Bs + w * 512);
    gload_lds16(Bw + (size_t)(n0 + r1) * K + kb + kk0, Bs + 2048 + w * 512);
    __syncthreads();
    bf16x8 af[4], bfr[4];
#pragma unroll
    for (int i = 0; i < 4; i++)
      af[i] = *(const bf16x8*)(As + (wr * 64 + i * 16 + lr) * 32 + lg * 8);
#pragma unroll
    for (int i = 0; i < 4; i++)
      bfr[i] = *(const bf16x8*)(Bs + (wc * 64 + i * 16 + lr) * 32 + lg * 8);
#pragma unroll
    for (int mi = 0; mi < 4; mi++)
#pragma unroll
      for (int ni = 0; ni < 4; ni++)
        acc[mi][ni] = MFMA16(af[mi], bfr[ni], acc[mi][ni]);
    __syncthreads();
  }
#pragma unroll
  for (int mi = 0; mi < 4; mi++)
#pragma unroll
    for (int ni = 0; ni < 4; ni++) {
      int col = n0 + wc * 64 + ni * 16 + lr;
      float bv = bias[col];
      if (outmode == 2) {
        int row0 = m0 + wr * 64 + mi * 16 + lg * 4;
        int bb = row0 >> 11, ss = row0 & (S_LEN - 1);
        u16x4 pk;
#pragma unroll
        for (int r = 0; r < 4; r++) pk[r] = f2bf((acc[mi][ni][r] + bv) * scale);
        *(u16x4*)((u16*)Cout + ((size_t)((bb * N_HEAD + (col >> 6)) * D_HEAD + (col & 63)) * S_LEN + ss)) = pk;
      } else {
#pragma unroll
        for (int r = 0; r < 4; r++) {
          int row = m0 + wr * 64 + mi * 16 + lg * 4 + r;
          float v = (acc[mi][ni][r] + bv) * scale;
          if (outmode == 1)
            ((float*)Cout)[(size_t)row * N + col] = v;
          else
            ((u16*)Cout)[(size_t)row * N + col] = f2bf(v);
        }
      }
    }
}

// Q scale folds 1/sqrt(64) * log2(e) so attention uses exp2 directly.
#define QSCALE 0.18033688011112042f

__global__ __launch_bounds__(256) void proj3_kernel(
    const u16* __restrict__ kbf, const u16* __restrict__ vbf, const u16* __restrict__ qbf,
    const u16* __restrict__ wkb, const u16* __restrict__ wvb, const u16* __restrict__ wqb,
    const float* __restrict__ bk, const float* __restrict__ bv, const float* __restrict__ bq,
    u16* __restrict__ kup, u16* __restrict__ vtg, u16* __restrict__ qup) {
  int z = blockIdx.z;
  if (z == 0)
    gemm_body(kbf, wkb, bk, kup, 1.0f, 0);
  else if (z == 1)
    gemm_body(vbf, wvb, bv, vtg, 1.0f, 2);
  else
    gemm_body(qbf, wqb, bq, qup, QSCALE, 0);
}

__global__ __launch_bounds__(256) void gemm_out_kernel(const u16* __restrict__ A,
                                                       const u16* __restrict__ Bw,
                                                       const float* __restrict__ bias,
                                                       float* __restrict__ C) {
  gemm_body(A, Bw, bias, C, 1.0f, 1);
}

// ---------------- attention pass 0: partial row sums, k-split x2 (r10, proven) ------
__global__ __launch_bounds__(256, 8) void attn_p0(const u16* __restrict__ Qup,
                                                  const u16* __restrict__ Kup,
                                                  const u32* __restrict__ mpack,
                                                  float* __restrict__ lsums) {
  __shared__ u16 kbuf[2][64 * 64];
  int tid = threadIdx.x;
  int w = tid >> 6, lane = tid & 63, lg = lane >> 4, lr = lane & 15;
  int fb = blockIdx.x;
  int logical = (fb & 7) * 256 + (fb >> 3);
  int khalf = logical & 1;
  int qb = (logical >> 1) & 31;
  int h = (logical >> 6) & 15;
  int b = logical >> 10;
  int q0 = qb * 64;
  int q = q0 + w * 16 + lr;
  const float NEGV = -100000000.0f;

  bf16x8 qf0, qf1;
  {
    const u16* qrow = Qup + (size_t)(b * S_LEN + q) * D_MODEL + h * D_HEAD;
    qf0 = *(const bf16x8*)(qrow + lg * 8);
    qf1 = *(const bf16x8*)(qrow + 32 + lg * 8);
  }
  const u16* Kb = Kup + (size_t)(b * S_LEN) * D_MODEL + h * D_HEAD;
  const u32* mrow = mpack + (size_t)(b * S_LEN + q) * (S_LEN / 32) + khalf * 32;

  int srow = tid >> 3;
  int schunk = (tid & 7) ^ (srow & 7);
  const u16* KgA = Kb + (size_t)(khalf * 1024 + srow) * D_MODEL + schunk * 8;
  const int sw = lr & 7;

#define STAGE_K0(bn, ktn)                                                   \
  do {                                                                      \
    const u16* _s = KgA + (size_t)(ktn) * 64 * D_MODEL;                     \
    gload_lds16(_s, &kbuf[bn][0] + w * 512);                                \
    gload_lds16(_s + (size_t)32 * D_MODEL, &kbuf[bn][2048] + w * 512);      \
  } while (0)

  float lsA = 0.f, lsB = 0.f;
#define P0_BODY(BN, MM)                                                     \
  {                                                                         \
    const u16* kc = &kbuf[BN][0];                                           \
    _Pragma("unroll") for (int t = 0; t < 4; t++) {                         \
      const u16* kr = kc + (t * 16 + lr) * 64;                              \
      bf16x8 k0 = *(const bf16x8*)(kr + ((lg ^ sw) << 3));                  \
      bf16x8 k1 = *(const bf16x8*)(kr + (((lg + 4) ^ sw) << 3));            \
      f32x4 a = {0.f, 0.f, 0.f, 0.f};                                       \
      a = MFMA16(k0, qf0, a);                                               \
      a = MFMA16(k1, qf1, a);                                               \
      u32 wbits = (t < 2) ? (MM).x : (MM).y;                                \
      _Pragma("unroll") for (int r = 0; r < 4; r++) {                       \
        int j = (t * 16 + lg * 4 + r) & 31;                                 \
        float s = ((wbits >> j) & 1u) ? NEGV : a[r];                        \
        if (r & 1) lsB += exp2f(s); else lsA += exp2f(s);                   \
      }                                                                     \
    }                                                                       \
  }

  uint2 mA, mB;
  mA = *(const uint2*)(mrow);
  STAGE_K0(0, 0);
  for (int it = 0; it < 7; it++) {
    int kt = it * 2;
    mB = *(const uint2*)(mrow + (kt + 1) * 2);
    STAGE_K0(1, kt + 1);
    WAITCNT(3);
    BAR();
    P0_BODY(0, mA);
    BAR();
    mA = *(const uint2*)(mrow + (kt + 2) * 2);
    STAGE_K0(0, kt + 2);
    WAITCNT(3);
    BAR();
    P0_BODY(1, mB);
    BAR();
  }
  mB = *(const uint2*)(mrow + 15 * 2);
  STAGE_K0(1, 15);
  WAITCNT(3);
  BAR();
  P0_BODY(0, mA);
  BAR();
  WAITCNT(0);
  BAR();
  P0_BODY(1, mB);

  float lsum = lsA + lsB;
  lsum += __shfl_xor(lsum, 16);
  lsum += __shfl_xor(lsum, 32);
  if (lg == 0) lsums[(size_t)khalf * 65536 + (size_t)(b * N_HEAD + h) * S_LEN + q] = lsum;
#undef STAGE_K0
#undef P0_BODY
}

// ---------------- attention pass 1: 64-q blocks, intra-block k-split, 100% occ ------
// grid = 1024 flat (XCD swizzled): (b, h, qx 0..31). 512 thr = 8 waves = 4 q-bands x
// 2 k-halves. Wave (band, half): q-rows [q0+band*16, +16), k in [half*1024, +1024),
// 32 tiles of KVBLK=32. Per half: K tile [32 k][64 dh] 4KB + V^T tile [64 dh][32 k]
// 4KB, both double-buffered (32 KB LDS total -> 4 blocks/CU = 32 waves = 100% occ).
// P stays in-register (16x16x16 PV); direct f32x4 attn stores; ctx halves combine
// through LDS (aliased over kbuf) after the loop.
__global__ __launch_bounds__(512, 8) void attn_p1(
    const u16* __restrict__ Qup, const u16* __restrict__ Kup, const u16* __restrict__ Vt,
    const u32* __restrict__ mpack, const float* __restrict__ lsums,
    float* __restrict__ attn_out, u16* __restrict__ ctx) {
  __shared__ u16 kbuf[2][2][32 * 64];  // [half][dbuf] 16 KB
  __shared__ u16 vbuf[2][2][64 * 32];  // [half][dbuf][dh][k] 16 KB
#if !defined(HAVE_MFMA_16x16x16)
  __shared__ u16 pbuf[8][16 * 32];     // 8 KB fallback
#endif
  int tid = threadIdx.x;
  int w = tid >> 6, lane = tid & 63, lg = lane >> 4, lr = lane & 15;
  int half = w >> 2, band = w & 3;
  int fb = blockIdx.x;
  int logical = (fb & 7) * 128 + (fb >> 3);  // 1024 % 8 == 0, bijective
  int qx = logical & 31;
  int h = (logical >> 5) & 15;
  int b = logical >> 9;
  int q0 = qx * 64;
  int q = q0 + band * 16 + lr;
  const float NEGV = -100000000.0f;

  bf16x8 qf0, qf1;
  {
    const u16* qrow = Qup + (size_t)(b * S_LEN + q) * D_MODEL + h * D_HEAD;
    qf0 = *(const bf16x8*)(qrow + lg * 8);
    qf1 = *(const bf16x8*)(qrow + 32 + lg * 8);
  }
  const u16* Kb = Kup + (size_t)(b * S_LEN) * D_MODEL + h * D_HEAD;
  const u16* Vb = Vt + (size_t)(b * N_HEAD + h) * D_HEAD * S_LEN;
  const u32* mrow = mpack + (size_t)(b * S_LEN + q) * (S_LEN / 32) + half * 32;
  float* attn_b = attn_out + ((size_t)(b * N_HEAD + h) * S_LEN + q) * S_LEN + half * 1024;

  float il2;
  {
    size_t idx = (size_t)(b * N_HEAD + h) * S_LEN + q;
    float tot = lsums[idx] + lsums[65536 + idx];
    il2 = tot > 0.f ? -__log2f(tot) : 0.f;
  }

  // staging (each half's 256 threads stage their own buffers; LDS dest linear/wave)
  int lt = tid & 255;
  int srow = lt >> 3;                        // K row 0..31
  int schunk = (tid & 7) ^ (srow & 7);       // K: 8 chunks/row, XOR row&7
  const u16* KgA = Kb + (size_t)(half * 1024 + srow) * D_MODEL + schunk * 8;
  int vrow = lt >> 2;                        // V row (dh) 0..63
  int vchunk = (tid & 3) ^ (vrow & 3);       // V: 4 chunks/row, XOR row&3
  const u16* VgA = Vb + (size_t)vrow * S_LEN + half * 1024 + vchunk * 8;
  const int swk = lr & 7;
  const int swv = lr & 3;

#define SK(bn, ktn) gload_lds16(KgA + (size_t)(ktn) * 32 * D_MODEL, &kbuf[half][bn][(w & 3) * 512])
#define SV(bn, ktn) gload_lds16(VgA + (size_t)(ktn) * 32, &vbuf[half][bn][(w & 3) * 512])

  f32x4 ctxacc[4] = {};

#if defined(HAVE_MFMA_16x16x16)
#define P1_BODY(BN, MM, KT)                                                 \
  {                                                                         \
    const u16* kc = &kbuf[half][BN][0];                                     \
    const u16* vc = &vbuf[half][BN][0];                                     \
    _Pragma("unroll") for (int t = 0; t < 2; t++) {                         \
      const u16* kr = kc + (t * 16 + lr) * 64;                              \
      bf16x8 k0 = *(const bf16x8*)(kr + ((lg ^ swk) << 3));                 \
      bf16x8 k1 = *(const bf16x8*)(kr + (((lg + 4) ^ swk) << 3));           \
      f32x4 a = {0.f, 0.f, 0.f, 0.f};                                       \
      a = MFMA16(k0, qf0, a);                                               \
      a = MFMA16(k1, qf1, a);                                               \
      f32x4 p;                                                              \
      u16x4 pb;                                                             \
      _Pragma("unroll") for (int r = 0; r < 4; r++) {                       \
        int j = t * 16 + lg * 4 + r;                                        \
        float s = (((MM) >> j) & 1u) ? NEGV : (a[r] + il2);                 \
        float pv = exp2f(s);                                                \
        p[r] = pv;                                                          \
        pb[r] = f2bf(pv);                                                   \
      }                                                                     \
      *(f32x4*)(attn_b + (KT) * 32 + t * 16 + lg * 4) = p;                  \
      s16x4 ap = {(short)pb[0], (short)pb[1], (short)pb[2], (short)pb[3]};  \
      _Pragma("unroll") for (int d = 0; d < 4; d++) {                       \
        s16x4 vf = *(const s16x4*)(vc + (d * 16 + lr) * 32 +                \
                                   (((t * 2 + (lg >> 1)) ^ swv) << 3) +     \
                                   ((lg & 1) << 2));                        \
        ctxacc[d] = MFMA_PV(ap, vf, ctxacc[d]);                             \
      }                                                                     \
    }                                                                       \
  }
#else
#define P1_BODY(BN, MM, KT)                                                 \
  {                                                                         \
    const u16* kc = &kbuf[half][BN][0];                                     \
    const u16* vc = &vbuf[half][BN][0];                                     \
    u16* pw = &pbuf[w][0];                                                  \
    _Pragma("unroll") for (int t = 0; t < 2; t++) {                         \
      const u16* kr = kc + (t * 16 + lr) * 64;                              \
      bf16x8 k0 = *(const bf16x8*)(kr + ((lg ^ swk) << 3));                 \
      bf16x8 k1 = *(const bf16x8*)(kr + (((lg + 4) ^ swk) << 3));           \
      f32x4 a = {0.f, 0.f, 0.f, 0.f};                                       \
      a = MFMA16(k0, qf0, a);                                               \
      a = MFMA16(k1, qf1, a);                                               \
      f32x4 p;                                                              \
      u16x4 pb;                                                             \
      _Pragma("unroll") for (int r = 0; r < 4; r++) {                       \
        int j = t * 16 + lg * 4 + r;                                        \
        float s = (((MM) >> j) & 1u) ? NEGV : (a[r] + il2);                 \
        float pv = exp2f(s);                                                \
        p[r] = pv;                                                          \
        pb[r] = f2bf(pv);                                                   \
      }                                                                     \
      *(f32x4*)(attn_b + (KT) * 32 + t * 16 + lg * 4) = p;                  \
      *(u16x4*)(pw + lr * 32 + (((t * 2 + (lg >> 1)) ^ swv) << 3) +         \
                ((lg & 1) << 2)) = pb;                                      \
    }                                                                       \
    bf16x8 pa = *(const bf16x8*)(pw + lr * 32 + ((lg ^ swv) << 3));         \
    _Pragma("unroll") for (int d = 0; d < 4; d++) {                         \
      bf16x8 v0 = *(const bf16x8*)(vc + (d * 16 + lr) * 32 +                \
                                   ((lg ^ swv) << 3));                      \
      ctxacc[d] = MFMA16(pa, v0, ctxacc[d]);                                \
    }                                                                       \
  }
#endif

  u32 mA, mB;
  mA = mrow[0];
  SK(0, 0);
  SV(0, 0);
  mB = mrow[1];
  SK(1, 1);
  SV(1, 1);
  WAITCNT(3);  // retire mask0+SK0+SV0; leave mask1+SK1+SV1
  BAR();
  P1_BODY(0, mA, 0);
  BAR();
  mA = mrow[2];
  SK(0, 2);
  SV(0, 2);
  WAITCNT(5);  // leave {2 stores body0, mask2, SK2, SV2}
  BAR();
  P1_BODY(1, mB, 1);
  BAR();
  for (int it = 1; it < 15; it++) {
    int kt = it * 2;
    mB = mrow[kt + 1];
    SK(1, kt + 1);
    SV(1, kt + 1);
    WAITCNT(5);
    BAR();
    P1_BODY(0, mA, kt);
    BAR();
    mA = mrow[kt + 2];
    SK(0, kt + 2);
    SV(0, kt + 2);
    WAITCNT(5);
    BAR();
    P1_BODY(1, mB, kt + 1);
    BAR();
  }
  // kt = 30 (stages tile 31)
  mB = mrow[31];
  SK(1, 31);
  SV(1, 31);
  WAITCNT(5);
  BAR();
  P1_BODY(0, mA, 30);
  BAR();
  // kt = 31
  WAITCNT(2);  // retire SK/SV(1,31)+mask31; leave body30's 2 stores
  BAR();
  P1_BODY(1, mB, 31);

  // ---- cross-half ctx combine via LDS (aliased over kbuf after loop) ----
  __syncthreads();
  float* red = (float*)&kbuf[0][0][0];  // 64 q-rows x 64 dh f32 = 16 KB
  if (half == 1) {
#pragma unroll
    for (int d = 0; d < 4; d++)
#pragma unroll
      for (int r = 0; r < 4; r++)
        red[(band * 16 + lg * 4 + r) * 64 + d * 16 + lr] = ctxacc[d][r];
  }
  __syncthreads();
  if (half == 0) {
#pragma unroll
    for (int d = 0; d < 4; d++)
#pragma unroll
      for (int r = 0; r < 4; r++) {
        int ql = band * 16 + lg * 4 + r;
        float v = ctxacc[d][r] + red[ql * 64 + d * 16 + lr];
        ctx[(size_t)(b * S_LEN + q0 + ql) * D_MODEL + h * D_HEAD + d * 16 + lr] = f2bf(v);
      }
  }
#undef SK
#undef SV
#undef P1_BODY
}

// ---------------- workspace layout (u16 units) ----------------
#define O_KBF 0u          // bf16 key input; reused for packed mask after projections
#define O_VBF 4194304u    // bf16 value input; reused for lsums (f32[2][65536]) after proj
#define O_QBF 8388608u
#define O_WQ 12582912u
#define O_WK 13631488u
#define O_WV 14680064u
#define O_WO 15728640u
#define O_QUP 16777216u
#define O_KUP 20971520u
#define O_VUP 25165824u   // V head-transposed [b][h][dh][s]
#define O_CTX 29360128u
// total = 33554432 u16 = 64 MiB

extern "C" void kernel_launch(void* const* d_in, const int* in_sizes, int n_in,
                              void* d_out, int out_size, void* d_ws, size_t ws_size,
                              hipStream_t stream) {
  const float* key = (const float*)d_in[0];
  const float* value = (const float*)d_in[1];
  const float* query = (const float*)d_in[2];
  const int* mask = (const int*)d_in[3];
  const float* Wq = (const float*)d_in[4];
  const float* bq = (const float*)d_in[5];
  const float* Wk = (const float*)d_in[6];
  const float* bk = (const float*)d_in[7];
  const float* Wv = (const float*)d_in[8];
  const float* bv = (const float*)d_in[9];
  const float* Wo = (const float*)d_in[10];
  const float* bo = (const float*)d_in[11];

  u16* ws = (u16*)d_ws;
  u16* kbf = ws + O_KBF;
  u16* vbf = ws + O_VBF;
  u16* qbf = ws + O_QBF;
  u16* wqb = ws + O_WQ;
  u16* wkb = ws + O_WK;
  u16* wvb = ws + O_WV;
  u16* wob = ws + O_WO;
  u16* qup = ws + O_QUP;
  u16* kup = ws + O_KUP;
  u16* vtg = ws + O_VUP;
  u16* ctxb = ws + O_CTX;
  u64* maskp = (u64*)kbf;              // dead kbf region after projections
  float* lsums = (float*)vbf;          // dead vbf region after projections

  float* out = (float*)d_out;
  float* attn = out + (size_t)N_BATCH * S_LEN * D_MODEL;

  cvt7_kernel<<<dim3(512, 7), 256, 0, stream>>>(key, value, query, Wq, Wk, Wv, Wo, kbf, vbf, qbf,
                                                wqb, wkb, wvb, wob);
  proj3_kernel<<<dim3(32, 8, 3), 256, 0, stream>>>(kbf, vbf, qbf, wkb, wvb, wqb, bk, bv, bq, kup,
                                                   vtg, qup);
  pack_mask<<<1024, 256, 0, stream>>>(mask, maskp);
  attn_p0<<<2048, 256, 0, stream>>>(qup, kup, (const u32*)maskp, lsums);
  attn_p1<<<1024, 512, 0, stream>>>(qup, kup, vtg, (const u32*)maskp, lsums, attn, ctxb);
  gemm_out_kernel<<<dim3(32, 8), 256, 0, stream>>>(ctxb, wob, bo, out);
}

// Round 13
// 357.841 us; speedup vs baseline: 1.5604x; 1.4531x over previous
//
#include <hip/hip_runtime.h>
#include <stdint.h>

#define S_LEN 2048
#define D_MODEL 1024
#define N_HEAD 16
#define D_HEAD 64
#define N_BATCH 2
#define M_TOK (N_BATCH * S_LEN)  // 4096

typedef unsigned short u16;
typedef unsigned int u32;
typedef unsigned long long u64;
typedef __attribute__((ext_vector_type(8))) short bf16x8;
typedef __attribute__((ext_vector_type(4))) short s16x4;
typedef __attribute__((ext_vector_type(4))) float f32x4;
typedef __attribute__((ext_vector_type(4))) unsigned short u16x4;

#define MFMA16(a, b, c) __builtin_amdgcn_mfma_f32_16x16x32_bf16((a), (b), (c), 0, 0, 0)

#if defined(__has_builtin)
#if __has_builtin(__builtin_amdgcn_mfma_f32_16x16x16bf16_1k)
#define HAVE_MFMA_16x16x16 1
#define MFMA_PV(a, b, c) __builtin_amdgcn_mfma_f32_16x16x16bf16_1k((a), (b), (c), 0, 0, 0)
#endif
#endif

#define WAITCNT(n) asm volatile("s_waitcnt vmcnt(" #n ")" ::: "memory")
#define BAR() __builtin_amdgcn_s_barrier()

__device__ __forceinline__ u16 f2bf(float f) {
  unsigned int u = __float_as_uint(f);
  u = (u + 0x7FFFu + ((u >> 16) & 1u)) >> 16;
  return (u16)u;
}

__device__ __forceinline__ void gload_lds16(const u16* g, u16* l) {
  __builtin_amdgcn_global_load_lds((const __attribute__((address_space(1))) void*)g,
                                   (__attribute__((address_space(3))) void*)l, 16, 0, 0);
}

// ---------------- fp32 -> bf16 convert, all 7 tensors in one launch ----------------
#define N4BIG (M_TOK * D_MODEL / 4)     // 1048576
#define N4W (D_MODEL * D_MODEL / 4)     // 262144
__global__ __launch_bounds__(256) void cvt7_kernel(
    const float* __restrict__ sk, const float* __restrict__ sv, const float* __restrict__ sq,
    const float* __restrict__ swq, const float* __restrict__ swk, const float* __restrict__ swv,
    const float* __restrict__ swo, u16* __restrict__ dk, u16* __restrict__ dv, u16* __restrict__ dq,
    u16* __restrict__ dwq, u16* __restrict__ dwk, u16* __restrict__ dwv, u16* __restrict__ dwo) {
  const float* s;
  u16* d;
  int n4;
  switch (blockIdx.y) {
    case 0: s = sk; d = dk; n4 = N4BIG; break;
    case 1: s = sv; d = dv; n4 = N4BIG; break;
    case 2: s = sq; d = dq; n4 = N4BIG; break;
    case 3: s = swq; d = dwq; n4 = N4W; break;
    case 4: s = swk; d = dwk; n4 = N4W; break;
    case 5: s = swv; d = dwv; n4 = N4W; break;
    default: s = swo; d = dwo; n4 = N4W; break;
  }
  int i = blockIdx.x * blockDim.x + threadIdx.x;
  int stride = gridDim.x * blockDim.x;
  for (; i < n4; i += stride) {
    float4 v = ((const float4*)s)[i];
    u16x4 o = {f2bf(v.x), f2bf(v.y), f2bf(v.z), f2bf(v.w)};
    ((u16x4*)d)[i] = o;
  }
}

// ---------------- mask bit-pack: int32[4096][2048] -> u64[4096][32] -----------------
__global__ __launch_bounds__(256) void pack_mask(const int* __restrict__ mask,
                                                 u64* __restrict__ packed) {
  int wid = (blockIdx.x * blockDim.x + threadIdx.x) >> 6;
  int lane = threadIdx.x & 63;
  int nw = (gridDim.x * blockDim.x) >> 6;
  const int NW64 = M_TOK * (S_LEN / 64);  // 131072
  for (int widx = wid; widx < NW64; widx += nw) {
    int m = mask[(size_t)widx * 64 + lane];
    u64 bits = __ballot(m != 0);
    if (lane == 0) packed[widx] = bits;
  }
}

// ---------------- GEMM body: C[M,N] = A[M,K]@Bw[N,K]^T, +bias, *scale ----------------
__device__ __forceinline__ void gemm_body(const u16* __restrict__ A, const u16* __restrict__ Bw,
                                          const float* __restrict__ bias, void* __restrict__ Cout,
                                          float scale, int outmode) {
  __shared__ u16 As[128 * 32];
  __shared__ u16 Bs[128 * 32];
  const int K = D_MODEL, N = D_MODEL;
  int tid = threadIdx.x;
  int w = tid >> 6, lane = tid & 63, lg = lane >> 4, lr = lane & 15;
  int m0 = blockIdx.x * 128, n0 = blockIdx.y * 128;
  int wr = w >> 1, wc = w & 1;
  f32x4 acc[4][4] = {};
  int r0 = tid >> 2;
  int r1 = 64 + (tid >> 2);
  int kk0 = (tid & 3) * 8;
  for (int kb = 0; kb < K; kb += 32) {
    gload_lds16(A + (size_t)(m0 + r0) * K + kb + kk0, As + w * 512);
    gload_lds16(A + (size_t)(m0 + r1) * K + kb + kk0, As + 2048 + w * 512);
    gload_lds16(Bw + (size_t)(n0 + r0) * K + kb + kk0, Bs + w * 512);
    gload_lds16(Bw + (size_t)(n0 + r1) * K + kb + kk0, Bs + 2048 + w * 512);
    __syncthreads();
    bf16x8 af[4], bfr[4];
#pragma unroll
    for (int i = 0; i < 4; i++)
      af[i] = *(const bf16x8*)(As + (wr * 64 + i * 16 + lr) * 32 + lg * 8);
#pragma unroll
    for (int i = 0; i < 4; i++)
      bfr[i] = *(const bf16x8*)(Bs + (wc * 64 + i * 16 + lr) * 32 + lg * 8);
#pragma unroll
    for (int mi = 0; mi < 4; mi++)
#pragma unroll
      for (int ni = 0; ni < 4; ni++)
        acc[mi][ni] = MFMA16(af[mi], bfr[ni], acc[mi][ni]);
    __syncthreads();
  }
#pragma unroll
  for (int mi = 0; mi < 4; mi++)
#pragma unroll
    for (int ni = 0; ni < 4; ni++) {
      int col = n0 + wc * 64 + ni * 16 + lr;
      float bv = bias[col];
      if (outmode == 2) {
        int row0 = m0 + wr * 64 + mi * 16 + lg * 4;
        int bb = row0 >> 11, ss = row0 & (S_LEN - 1);
        u16x4 pk;
#pragma unroll
        for (int r = 0; r < 4; r++) pk[r] = f2bf((acc[mi][ni][r] + bv) * scale);
        *(u16x4*)((u16*)Cout + ((size_t)((bb * N_HEAD + (col >> 6)) * D_HEAD + (col & 63)) * S_LEN + ss)) = pk;
      } else {
#pragma unroll
        for (int r = 0; r < 4; r++) {
          int row = m0 + wr * 64 + mi * 16 + lg * 4 + r;
          float v = (acc[mi][ni][r] + bv) * scale;
          if (outmode == 1)
            ((float*)Cout)[(size_t)row * N + col] = v;
          else
            ((u16*)Cout)[(size_t)row * N + col] = f2bf(v);
        }
      }
    }
}

// Q scale folds 1/sqrt(64) * log2(e) so attention uses exp2 directly.
#define QSCALE 0.18033688011112042f

__global__ __launch_bounds__(256) void proj3_kernel(
    const u16* __restrict__ kbf, const u16* __restrict__ vbf, const u16* __restrict__ qbf,
    const u16* __restrict__ wkb, const u16* __restrict__ wvb, const u16* __restrict__ wqb,
    const float* __restrict__ bk, const float* __restrict__ bv, const float* __restrict__ bq,
    u16* __restrict__ kup, u16* __restrict__ vtg, u16* __restrict__ qup) {
  int z = blockIdx.z;
  if (z == 0)
    gemm_body(kbf, wkb, bk, kup, 1.0f, 0);
  else if (z == 1)
    gemm_body(vbf, wvb, bv, vtg, 1.0f, 2);
  else
    gemm_body(qbf, wqb, bq, qup, QSCALE, 0);
}

__global__ __launch_bounds__(256) void gemm_out_kernel(const u16* __restrict__ A,
                                                       const u16* __restrict__ Bw,
                                                       const float* __restrict__ bias,
                                                       float* __restrict__ C) {
  gemm_body(A, Bw, bias, C, 1.0f, 1);
}

// ---------------- attention pass 0: partial row sums, k-split x2 (r10, proven) ------
__global__ __launch_bounds__(256, 8) void attn_p0(const u16* __restrict__ Qup,
                                                  const u16* __restrict__ Kup,
                                                  const u32* __restrict__ mpack,
                                                  float* __restrict__ lsums) {
  __shared__ u16 kbuf[2][64 * 64];
  int tid = threadIdx.x;
  int w = tid >> 6, lane = tid & 63, lg = lane >> 4, lr = lane & 15;
  int fb = blockIdx.x;
  int logical = (fb & 7) * 256 + (fb >> 3);
  int khalf = logical & 1;
  int qb = (logical >> 1) & 31;
  int h = (logical >> 6) & 15;
  int b = logical >> 10;
  int q0 = qb * 64;
  int q = q0 + w * 16 + lr;
  const float NEGV = -100000000.0f;

  bf16x8 qf0, qf1;
  {
    const u16* qrow = Qup + (size_t)(b * S_LEN + q) * D_MODEL + h * D_HEAD;
    qf0 = *(const bf16x8*)(qrow + lg * 8);
    qf1 = *(const bf16x8*)(qrow + 32 + lg * 8);
  }
  const u16* Kb = Kup + (size_t)(b * S_LEN) * D_MODEL + h * D_HEAD;
  const u32* mrow = mpack + (size_t)(b * S_LEN + q) * (S_LEN / 32) + khalf * 32;

  int srow = tid >> 3;
  int schunk = (tid & 7) ^ (srow & 7);
  const u16* KgA = Kb + (size_t)(khalf * 1024 + srow) * D_MODEL + schunk * 8;
  const int sw = lr & 7;

#define STAGE_K0(bn, ktn)                                                   \
  do {                                                                      \
    const u16* _s = KgA + (size_t)(ktn) * 64 * D_MODEL;                     \
    gload_lds16(_s, &kbuf[bn][0] + w * 512);                                \
    gload_lds16(_s + (size_t)32 * D_MODEL, &kbuf[bn][2048] + w * 512);      \
  } while (0)

  float lsA = 0.f, lsB = 0.f;
#define P0_BODY(BN, MM)                                                     \
  {                                                                         \
    const u16* kc = &kbuf[BN][0];                                           \
    _Pragma("unroll") for (int t = 0; t < 4; t++) {                         \
      const u16* kr = kc + (t * 16 + lr) * 64;                              \
      bf16x8 k0 = *(const bf16x8*)(kr + ((lg ^ sw) << 3));                  \
      bf16x8 k1 = *(const bf16x8*)(kr + (((lg + 4) ^ sw) << 3));            \
      f32x4 a = {0.f, 0.f, 0.f, 0.f};                                       \
      a = MFMA16(k0, qf0, a);                                               \
      a = MFMA16(k1, qf1, a);                                               \
      u32 wbits = (t < 2) ? (MM).x : (MM).y;                                \
      _Pragma("unroll") for (int r = 0; r < 4; r++) {                       \
        int j = (t * 16 + lg * 4 + r) & 31;                                 \
        float s = ((wbits >> j) & 1u) ? NEGV : a[r];                        \
        if (r & 1) lsB += exp2f(s); else lsA += exp2f(s);                   \
      }                                                                     \
    }                                                                       \
  }

  uint2 mA, mB;
  mA = *(const uint2*)(mrow);
  STAGE_K0(0, 0);
  for (int it = 0; it < 7; it++) {
    int kt = it * 2;
    mB = *(const uint2*)(mrow + (kt + 1) * 2);
    STAGE_K0(1, kt + 1);
    WAITCNT(3);
    BAR();
    P0_BODY(0, mA);
    BAR();
    mA = *(const uint2*)(mrow + (kt + 2) * 2);
    STAGE_K0(0, kt + 2);
    WAITCNT(3);
    BAR();
    P0_BODY(1, mB);
    BAR();
  }
  mB = *(const uint2*)(mrow + 15 * 2);
  STAGE_K0(1, 15);
  WAITCNT(3);
  BAR();
  P0_BODY(0, mA);
  BAR();
  WAITCNT(0);
  BAR();
  P0_BODY(1, mB);

  float lsum = lsA + lsB;
  lsum += __shfl_xor(lsum, 16);
  lsum += __shfl_xor(lsum, 32);
  if (lg == 0) lsums[(size_t)khalf * 65536 + (size_t)(b * N_HEAD + h) * S_LEN + q] = lsum;
#undef STAGE_K0
#undef P0_BODY
}

// ---------------- attention pass 1: 4-wave blocks, 64 q-rows, full k ----------------
// grid = 1024 flat (XCD swizzled): (b, h, qx 0..31). 256 thr = 4 waves; wave w owns
// q-rows [q0+16w, +16), full k, 32 tiles of KVBLK=64. K tile [64 k][64 dh] 8KB +
// V^T tile [64 dh][64 k] 8KB, both double-buffered = 32 KB -> 5 blocks/CU
// (LDS-capped) = 20 waves/CU in 5 INDEPENDENT 4-wave barrier groups. In-register
// P->PV (16x16x16); direct f32x4 attn stores; counted vmcnt, stores never drained.
__global__ __launch_bounds__(256, 5) void attn_p1(
    const u16* __restrict__ Qup, const u16* __restrict__ Kup, const u16* __restrict__ Vt,
    const u32* __restrict__ mpack, const float* __restrict__ lsums,
    float* __restrict__ attn_out, u16* __restrict__ ctx) {
  __shared__ u16 kbuf[2][64 * 64];  // 16 KB
  __shared__ u16 vbuf[2][64 * 64];  // 16 KB
#if !defined(HAVE_MFMA_16x16x16)
  __shared__ u16 pbuf[4][16 * 64];  // 8 KB fallback
#endif
  int tid = threadIdx.x;
  int w = tid >> 6, lane = tid & 63, lg = lane >> 4, lr = lane & 15;
  int fb = blockIdx.x;
  int logical = (fb & 7) * 128 + (fb >> 3);  // 1024 % 8 == 0, bijective
  int qx = logical & 31;
  int h = (logical >> 5) & 15;
  int b = logical >> 9;
  int q0 = qx * 64;
  int q = q0 + w * 16 + lr;
  const float NEGV = -100000000.0f;

  bf16x8 qf0, qf1;
  {
    const u16* qrow = Qup + (size_t)(b * S_LEN + q) * D_MODEL + h * D_HEAD;
    qf0 = *(const bf16x8*)(qrow + lg * 8);
    qf1 = *(const bf16x8*)(qrow + 32 + lg * 8);
  }
  const u16* Kb = Kup + (size_t)(b * S_LEN) * D_MODEL + h * D_HEAD;
  const u16* Vb = Vt + (size_t)(b * N_HEAD + h) * D_HEAD * S_LEN;
  const u32* mrow = mpack + (size_t)(b * S_LEN + q) * (S_LEN / 32);
  float* attn_b = attn_out + ((size_t)(b * N_HEAD + h) * S_LEN + q) * S_LEN;

  float il2;
  {
    size_t idx = (size_t)(b * N_HEAD + h) * S_LEN + q;
    float tot = lsums[idx] + lsums[65536 + idx];
    il2 = tot > 0.f ? -__log2f(tot) : 0.f;
  }

  // staging: 256 thr -> (row = tid>>3 in 0..31, chunk = (tid&7)^(row&7)); 2 gloads
  // per tile (rows 0..31, 32..63); LDS dest linear per wave.
  int srow = tid >> 3;
  int schunk = (tid & 7) ^ (srow & 7);
  const u16* KgA = Kb + (size_t)srow * D_MODEL + schunk * 8;
  const u16* VgA = Vb + (size_t)srow * S_LEN + schunk * 8;
  const int sw = lr & 7;

#define SK(bn, ktn)                                                          \
  do {                                                                       \
    const u16* _s = KgA + (size_t)(ktn) * 64 * D_MODEL;                      \
    gload_lds16(_s, &kbuf[bn][0] + w * 512);                                 \
    gload_lds16(_s + (size_t)32 * D_MODEL, &kbuf[bn][2048] + w * 512);       \
  } while (0)
#define SV(bn, ktn)                                                          \
  do {                                                                       \
    const u16* _s = VgA + (size_t)(ktn) * 64;                                \
    gload_lds16(_s, &vbuf[bn][0] + w * 512);                                 \
    gload_lds16(_s + (size_t)32 * S_LEN, &vbuf[bn][2048] + w * 512);         \
  } while (0)

  f32x4 ctxacc[4] = {};

#if defined(HAVE_MFMA_16x16x16)
#define P1_BODY(BN, MM, KT)                                                  \
  {                                                                          \
    const u16* kc = &kbuf[BN][0];                                            \
    const u16* vc = &vbuf[BN][0];                                            \
    _Pragma("unroll") for (int t = 0; t < 4; t++) {                          \
      const u16* kr = kc + (t * 16 + lr) * 64;                               \
      bf16x8 k0 = *(const bf16x8*)(kr + ((lg ^ sw) << 3));                   \
      bf16x8 k1 = *(const bf16x8*)(kr + (((lg + 4) ^ sw) << 3));             \
      f32x4 a = {0.f, 0.f, 0.f, 0.f};                                        \
      a = MFMA16(k0, qf0, a);                                                \
      a = MFMA16(k1, qf1, a);                                                \
      u32 wbits = (t < 2) ? (MM).x : (MM).y;                                 \
      f32x4 p;                                                               \
      u16x4 pb;                                                              \
      _Pragma("unroll") for (int r = 0; r < 4; r++) {                        \
        int j = (t * 16 + lg * 4 + r) & 31;                                  \
        float s = ((wbits >> j) & 1u) ? NEGV : (a[r] + il2);                 \
        float pv = exp2f(s);                                                 \
        p[r] = pv;                                                           \
        pb[r] = f2bf(pv);                                                    \
      }                                                                      \
      *(f32x4*)(attn_b + (KT) * 64 + t * 16 + lg * 4) = p;                   \
      s16x4 ap = {(short)pb[0], (short)pb[1], (short)pb[2], (short)pb[3]};   \
      _Pragma("unroll") for (int d = 0; d < 4; d++) {                        \
        s16x4 vf = *(const s16x4*)(vc + (d * 16 + lr) * 64 +                 \
                                   (((t * 2 + (lg >> 1)) ^ sw) << 3) +       \
                                   ((lg & 1) << 2));                         \
        ctxacc[d] = MFMA_PV(ap, vf, ctxacc[d]);                              \
      }                                                                      \
    }                                                                        \
  }
#else
#define P1_BODY(BN, MM, KT)                                                  \
  {                                                                          \
    const u16* kc = &kbuf[BN][0];                                            \
    const u16* vc = &vbuf[BN][0];                                            \
    u16* pw = &pbuf[w][0];                                                   \
    _Pragma("unroll") for (int t = 0; t < 4; t++) {                          \
      const u16* kr = kc + (t * 16 + lr) * 64;                               \
      bf16x8 k0 = *(const bf16x8*)(kr + ((lg ^ sw) << 3));                   \
      bf16x8 k1 = *(const bf16x8*)(kr + (((lg + 4) ^ sw) << 3));             \
      f32x4 a = {0.f, 0.f, 0.f, 0.f};                                        \
      a = MFMA16(k0, qf0, a);                                                \
      a = MFMA16(k1, qf1, a);                                                \
      u32 wbits = (t < 2) ? (MM).x : (MM).y;                                 \
      f32x4 p;                                                               \
      u16x4 pb;                                                              \
      _Pragma("unroll") for (int r = 0; r < 4; r++) {                        \
        int j = (t * 16 + lg * 4 + r) & 31;                                  \
        float s = ((wbits >> j) & 1u) ? NEGV : (a[r] + il2);                 \
        float pv = exp2f(s);                                                 \
        p[r] = pv;                                                           \
        pb[r] = f2bf(pv);                                                    \
      }                                                                      \
      *(f32x4*)(attn_b + (KT) * 64 + t * 16 + lg * 4) = p;                   \
      *(u16x4*)(pw + lr * 64 + (((t * 2 + (lg >> 1)) ^ sw) << 3) +           \
                ((lg & 1) << 2)) = pb;                                       \
    }                                                                        \
    bf16x8 pa0 = *(const bf16x8*)(pw + lr * 64 + ((lg ^ sw) << 3));          \
    bf16x8 pa1 = *(const bf16x8*)(pw + lr * 64 + (((lg + 4) ^ sw) << 3));    \
    _Pragma("unroll") for (int d = 0; d < 4; d++) {                          \
      const u16* vr = vc + (d * 16 + lr) * 64;                               \
      bf16x8 v0 = *(const bf16x8*)(vr + ((lg ^ sw) << 3));                   \
      bf16x8 v1 = *(const bf16x8*)(vr + (((lg + 4) ^ sw) << 3));             \
      ctxacc[d] = MFMA16(pa0, v0, ctxacc[d]);                                \
      ctxacc[d] = MFMA16(pa1, v1, ctxacc[d]);                                \
    }                                                                        \
  }
#endif

  // ledger: stage(tile) = {SK(2), SV(2)}; +mask(1) = 5 ops per prefetch group.
  // steady WAITCNT(9) = {4 stores of prev body} + {5-op next stage} left in flight;
  // retires current tile's stage. Stores retire naturally two tiles later.
  uint2 mA, mB;
  mA = *(const uint2*)(mrow);
  SK(0, 0);
  SV(0, 0);
  mB = *(const uint2*)(mrow + 1 * 2);
  SK(1, 1);
  SV(1, 1);
  WAITCNT(5);
  BAR();
  P1_BODY(0, mA, 0);
  BAR();
  mA = *(const uint2*)(mrow + 2 * 2);
  SK(0, 2);
  SV(0, 2);
  WAITCNT(9);
  BAR();
  P1_BODY(1, mB, 1);
  BAR();
  for (int it = 1; it < 15; it++) {
    int kt = it * 2;
    mB = *(const uint2*)(mrow + (kt + 1) * 2);
    SK(1, kt + 1);
    SV(1, kt + 1);
    WAITCNT(9);
    BAR();
    P1_BODY(0, mA, kt);
    BAR();
    mA = *(const uint2*)(mrow + (kt + 2) * 2);
    SK(0, kt + 2);
    SV(0, kt + 2);
    WAITCNT(9);
    BAR();
    P1_BODY(1, mB, kt + 1);
    BAR();
  }
  // tile 30 (stage 31)
  mB = *(const uint2*)(mrow + 31 * 2);
  SK(1, 31);
  SV(1, 31);
  WAITCNT(9);
  BAR();
  P1_BODY(0, mA, 30);
  BAR();
  // tile 31: retire stage 31 (+mask), leave body-30's 4 stores in flight
  WAITCNT(4);
  BAR();
  P1_BODY(1, mB, 31);

  // context out: [B,S,H,DH] == [M_TOK, D_MODEL] row-major
#pragma unroll
  for (int d = 0; d < 4; d++)
#pragma unroll
    for (int r = 0; r < 4; r++) {
      int sq = q0 + w * 16 + lg * 4 + r;
      ctx[(size_t)(b * S_LEN + sq) * D_MODEL + h * D_HEAD + d * 16 + lr] = f2bf(ctxacc[d][r]);
    }
#undef SK
#undef SV
#undef P1_BODY
}

// ---------------- workspace layout (u16 units) ----------------
#define O_KBF 0u          // bf16 key input; reused for packed mask after projections
#define O_VBF 4194304u    // bf16 value input; reused for lsums (f32[2][65536]) after proj
#define O_QBF 8388608u
#define O_WQ 12582912u
#define O_WK 13631488u
#define O_WV 14680064u
#define O_WO 15728640u
#define O_QUP 16777216u
#define O_KUP 20971520u
#define O_VUP 25165824u   // V head-transposed [b][h][dh][s]
#define O_CTX 29360128u
// total = 33554432 u16 = 64 MiB

extern "C" void kernel_launch(void* const* d_in, const int* in_sizes, int n_in,
                              void* d_out, int out_size, void* d_ws, size_t ws_size,
                              hipStream_t stream) {
  const float* key = (const float*)d_in[0];
  const float* value = (const float*)d_in[1];
  const float* query = (const float*)d_in[2];
  const int* mask = (const int*)d_in[3];
  const float* Wq = (const float*)d_in[4];
  const float* bq = (const float*)d_in[5];
  const float* Wk = (const float*)d_in[6];
  const float* bk = (const float*)d_in[7];
  const float* Wv = (const float*)d_in[8];
  const float* bv = (const float*)d_in[9];
  const float* Wo = (const float*)d_in[10];
  const float* bo = (const float*)d_in[11];

  u16* ws = (u16*)d_ws;
  u16* kbf = ws + O_KBF;
  u16* vbf = ws + O_VBF;
  u16* qbf = ws + O_QBF;
  u16* wqb = ws + O_WQ;
  u16* wkb = ws + O_WK;
  u16* wvb = ws + O_WV;
  u16* wob = ws + O_WO;
  u16* qup = ws + O_QUP;
  u16* kup = ws + O_KUP;
  u16* vtg = ws + O_VUP;
  u16* ctxb = ws + O_CTX;
  u64* maskp = (u64*)kbf;              // dead kbf region after projections
  float* lsums = (float*)vbf;          // dead vbf region after projections

  float* out = (float*)d_out;
  float* attn = out + (size_t)N_BATCH * S_LEN * D_MODEL;

  cvt7_kernel<<<dim3(512, 7), 256, 0, stream>>>(key, value, query, Wq, Wk, Wv, Wo, kbf, vbf, qbf,
                                                wqb, wkb, wvb, wob);
  proj3_kernel<<<dim3(32, 8, 3), 256, 0, stream>>>(kbf, vbf, qbf, wkb, wvb, wqb, bk, bv, bq, kup,
                                                   vtg, qup);
  pack_mask<<<1024, 256, 0, stream>>>(mask, maskp);
  attn_p0<<<2048, 256, 0, stream>>>(qup, kup, (const u32*)maskp, lsums);
  attn_p1<<<1024, 256, 0, stream>>>(qup, kup, vtg, (const u32*)maskp, lsums, attn, ctxb);
  gemm_out_kernel<<<dim3(32, 8), 256, 0, stream>>>(ctxb, wob, bo, out);
}

// Round 15
// 334.845 us; speedup vs baseline: 1.6676x; 1.0687x over previous
//
#include <hip/hip_runtime.h>
#include <stdint.h>

#define S_LEN 2048
#define D_MODEL 1024
#define N_HEAD 16
#define D_HEAD 64
#define N_BATCH 2
#define M_TOK (N_BATCH * S_LEN)  // 4096

typedef unsigned short u16;
typedef unsigned int u32;
typedef unsigned long long u64;
typedef __attribute__((ext_vector_type(8))) short bf16x8;
typedef __attribute__((ext_vector_type(4))) short s16x4;
typedef __attribute__((ext_vector_type(4))) float f32x4;
typedef __attribute__((ext_vector_type(4))) unsigned short u16x4;

#define MFMA16(a, b, c) __builtin_amdgcn_mfma_f32_16x16x32_bf16((a), (b), (c), 0, 0, 0)

#if defined(__has_builtin)
#if __has_builtin(__builtin_amdgcn_mfma_f32_16x16x16bf16_1k)
#define HAVE_MFMA_16x16x16 1
#define MFMA_PV(a, b, c) __builtin_amdgcn_mfma_f32_16x16x16bf16_1k((a), (b), (c), 0, 0, 0)
#endif
#endif

#define WAITCNT(n) asm volatile("s_waitcnt vmcnt(" #n ")" ::: "memory")
#define BAR() __builtin_amdgcn_s_barrier()

__device__ __forceinline__ u16 f2bf(float f) {
  unsigned int u = __float_as_uint(f);
  u = (u + 0x7FFFu + ((u >> 16) & 1u)) >> 16;
  return (u16)u;
}

__device__ __forceinline__ void gload_lds16(const u16* g, u16* l) {
  __builtin_amdgcn_global_load_lds((const __attribute__((address_space(1))) void*)g,
                                   (__attribute__((address_space(3))) void*)l, 16, 0, 0);
}

// ---------------- fp32 -> bf16 convert, all 7 tensors in one launch ----------------
#define N4BIG (M_TOK * D_MODEL / 4)     // 1048576
#define N4W (D_MODEL * D_MODEL / 4)     // 262144
__global__ __launch_bounds__(256) void cvt7_kernel(
    const float* __restrict__ sk, const float* __restrict__ sv, const float* __restrict__ sq,
    const float* __restrict__ swq, const float* __restrict__ swk, const float* __restrict__ swv,
    const float* __restrict__ swo, u16* __restrict__ dk, u16* __restrict__ dv, u16* __restrict__ dq,
    u16* __restrict__ dwq, u16* __restrict__ dwk, u16* __restrict__ dwv, u16* __restrict__ dwo) {
  const float* s;
  u16* d;
  int n4;
  switch (blockIdx.y) {
    case 0: s = sk; d = dk; n4 = N4BIG; break;
    case 1: s = sv; d = dv; n4 = N4BIG; break;
    case 2: s = sq; d = dq; n4 = N4BIG; break;
    case 3: s = swq; d = dwq; n4 = N4W; break;
    case 4: s = swk; d = dwk; n4 = N4W; break;
    case 5: s = swv; d = dwv; n4 = N4W; break;
    default: s = swo; d = dwo; n4 = N4W; break;
  }
  int i = blockIdx.x * blockDim.x + threadIdx.x;
  int stride = gridDim.x * blockDim.x;
  for (; i < n4; i += stride) {
    float4 v = ((const float4*)s)[i];
    u16x4 o = {f2bf(v.x), f2bf(v.y), f2bf(v.z), f2bf(v.w)};
    ((u16x4*)d)[i] = o;
  }
}

// ---------------- mask bit-pack: int32[4096][2048] -> u64[4096][32] -----------------
__global__ __launch_bounds__(256) void pack_mask(const int* __restrict__ mask,
                                                 u64* __restrict__ packed) {
  int wid = (blockIdx.x * blockDim.x + threadIdx.x) >> 6;
  int lane = threadIdx.x & 63;
  int nw = (gridDim.x * blockDim.x) >> 6;
  const int NW64 = M_TOK * (S_LEN / 64);  // 131072
  for (int widx = wid; widx < NW64; widx += nw) {
    int m = mask[(size_t)widx * 64 + lane];
    u64 bits = __ballot(m != 0);
    if (lane == 0) packed[widx] = bits;
  }
}

// ---------------- GEMM body: C[M,N] = A[M,K]@Bw[N,K]^T, +bias, *scale ----------------
__device__ __forceinline__ void gemm_body(const u16* __restrict__ A, const u16* __restrict__ Bw,
                                          const float* __restrict__ bias, void* __restrict__ Cout,
                                          float scale, int outmode) {
  __shared__ u16 As[128 * 32];
  __shared__ u16 Bs[128 * 32];
  const int K = D_MODEL, N = D_MODEL;
  int tid = threadIdx.x;
  int w = tid >> 6, lane = tid & 63, lg = lane >> 4, lr = lane & 15;
  int m0 = blockIdx.x * 128, n0 = blockIdx.y * 128;
  int wr = w >> 1, wc = w & 1;
  f32x4 acc[4][4] = {};
  int r0 = tid >> 2;
  int r1 = 64 + (tid >> 2);
  int kk0 = (tid & 3) * 8;
  for (int kb = 0; kb < K; kb += 32) {
    gload_lds16(A + (size_t)(m0 + r0) * K + kb + kk0, As + w * 512);
    gload_lds16(A + (size_t)(m0 + r1) * K + kb + kk0, As + 2048 + w * 512);
    gload_lds16(Bw + (size_t)(n0 + r0) * K + kb + kk0, Bs + w * 512);
    gload_lds16(Bw + (size_t)(n0 + r1) * K + kb + kk0, Bs + 2048 + w * 512);
    __syncthreads();
    bf16x8 af[4], bfr[4];
#pragma unroll
    for (int i = 0; i < 4; i++)
      af[i] = *(const bf16x8*)(As + (wr * 64 + i * 16 + lr) * 32 + lg * 8);
#pragma unroll
    for (int i = 0; i < 4; i++)
      bfr[i] = *(const bf16x8*)(Bs + (wc * 64 + i * 16 + lr) * 32 + lg * 8);
#pragma unroll
    for (int mi = 0; mi < 4; mi++)
#pragma unroll
      for (int ni = 0; ni < 4; ni++)
        acc[mi][ni] = MFMA16(af[mi], bfr[ni], acc[mi][ni]);
    __syncthreads();
  }
#pragma unroll
  for (int mi = 0; mi < 4; mi++)
#pragma unroll
    for (int ni = 0; ni < 4; ni++) {
      int col = n0 + wc * 64 + ni * 16 + lr;
      float bv = bias[col];
      if (outmode == 2) {
        int row0 = m0 + wr * 64 + mi * 16 + lg * 4;
        int bb = row0 >> 11, ss = row0 & (S_LEN - 1);
        u16x4 pk;
#pragma unroll
        for (int r = 0; r < 4; r++) pk[r] = f2bf((acc[mi][ni][r] + bv) * scale);
        *(u16x4*)((u16*)Cout + ((size_t)((bb * N_HEAD + (col >> 6)) * D_HEAD + (col & 63)) * S_LEN + ss)) = pk;
      } else {
#pragma unroll
        for (int r = 0; r < 4; r++) {
          int row = m0 + wr * 64 + mi * 16 + lg * 4 + r;
          float v = (acc[mi][ni][r] + bv) * scale;
          if (outmode == 1)
            ((float*)Cout)[(size_t)row * N + col] = v;
          else
            ((u16*)Cout)[(size_t)row * N + col] = f2bf(v);
        }
      }
    }
}

// Q scale folds 1/sqrt(64) * log2(e) so attention uses exp2 directly.
#define QSCALE 0.18033688011112042f

__global__ __launch_bounds__(256) void proj3_kernel(
    const u16* __restrict__ kbf, const u16* __restrict__ vbf, const u16* __restrict__ qbf,
    const u16* __restrict__ wkb, const u16* __restrict__ wvb, const u16* __restrict__ wqb,
    const float* __restrict__ bk, const float* __restrict__ bv, const float* __restrict__ bq,
    u16* __restrict__ kup, u16* __restrict__ vtg, u16* __restrict__ qup) {
  int z = blockIdx.z;
  if (z == 0)
    gemm_body(kbf, wkb, bk, kup, 1.0f, 0);
  else if (z == 1)
    gemm_body(vbf, wvb, bv, vtg, 1.0f, 2);
  else
    gemm_body(qbf, wqb, bq, qup, QSCALE, 0);
}

__global__ __launch_bounds__(256) void gemm_out_kernel(const u16* __restrict__ A,
                                                       const u16* __restrict__ Bw,
                                                       const float* __restrict__ bias,
                                                       float* __restrict__ C) {
  gemm_body(A, Bw, bias, C, 1.0f, 1);
}

// ---------------- fused attention: pass-0 KBLK=256, pass-1 = r8 verbatim ------------
// grid = 512 flat blocks (XCD-chunk swizzled), 512 threads = 8 waves. Wave w owns
// q-rows [q0+16w, +16), full k. LDS: sbuf[2][16384] (64 KB).
//   pass 0: KBLK=256, tile = whole 32KB buffer [256 k][64 dh]; 8 tiles, 16 barriers.
//           Waits leave only intrinsic-counted ops (4 gloads + masks); vmcnt(4)
//           over-retires next group's masks -> robust (never under-retires).
//   pass 1: KVBLK=128, K view sbuf[bn][0..8191], V^T view sbuf[bn][8192..16383];
//           r8 ledger verbatim: steady vmcnt(5) (retires all older than the newest
//           5-op group -- robust to compiler-lowered store counts), tail vmcnt(8).
__global__ __launch_bounds__(512, 4) void attn_kernel(
    const u16* __restrict__ Qup, const u16* __restrict__ Kup, const u16* __restrict__ Vt,
    const u32* __restrict__ mpack, float* __restrict__ attn_out, u16* __restrict__ ctx) {
  __shared__ u16 sbuf[2][16384];  // 64 KB, aliased by both passes
#if !defined(HAVE_MFMA_16x16x16)
  __shared__ u16 pbuf[8][16 * 64];
#endif
  int tid = threadIdx.x;
  int w = tid >> 6, lane = tid & 63, lg = lane >> 4, lr = lane & 15;

  // XCD-chunked bijective swizzle (512 % 8 == 0)
  int fb = blockIdx.x;
  int logical = (fb & 7) * 64 + (fb >> 3);
  int qx = logical & 15;
  int h = (logical >> 4) & 15;
  int b = logical >> 8;
  int q0 = qx * 128;
  int q = q0 + w * 16 + lr;
  const float NEGV = -100000000.0f;

  bf16x8 qf0, qf1;
  {
    const u16* qrow = Qup + (size_t)(b * S_LEN + q) * D_MODEL + h * D_HEAD;
    qf0 = *(const bf16x8*)(qrow + lg * 8);
    qf1 = *(const bf16x8*)(qrow + 32 + lg * 8);
  }
  const u16* Kb = Kup + (size_t)(b * S_LEN) * D_MODEL + h * D_HEAD;
  const u16* Vb = Vt + (size_t)(b * N_HEAD + h) * D_HEAD * S_LEN;
  const u32* mrow = mpack + (size_t)(b * S_LEN + q) * (S_LEN / 32);
  float* attn_b = attn_out + ((size_t)(b * N_HEAD + h) * S_LEN + q) * S_LEN;

  // staging: thread -> (row, chunk) with pre-swizzled global source; LDS dest linear.
  int krow = tid >> 3;                       // 0..63 (repeat gloads: +64k rows, same &7)
  int kchunk = (tid & 7) ^ (krow & 7);
  const u16* KgA = Kb + (size_t)krow * D_MODEL + kchunk * 8;
  int vrow = tid >> 4;                       // 0..31 (second gload: +32, same &7)
  int vchunk = (tid & 15) ^ (vrow & 7);
  const u16* VgA = Vb + (size_t)vrow * S_LEN + vchunk * 8;
  const int sw = lr & 7;                     // read-side swizzle key

  // ---- pass-0 staging: KBLK=256 -> 4 gloads into the full 32KB buffer ----
#define SK0(bn, ktn)                                                        \
  do {                                                                      \
    const u16* _s = KgA + (size_t)(ktn) * 256 * D_MODEL;                    \
    gload_lds16(_s, &sbuf[bn][0] + w * 512);                                \
    gload_lds16(_s + (size_t)64 * D_MODEL, &sbuf[bn][4096] + w * 512);      \
    gload_lds16(_s + (size_t)128 * D_MODEL, &sbuf[bn][8192] + w * 512);     \
    gload_lds16(_s + (size_t)192 * D_MODEL, &sbuf[bn][12288] + w * 512);    \
  } while (0)
  // ---- pass-1 staging: KVBLK=128 (r8 layout) ----
#define SK1(bn, ktn)                                                        \
  do {                                                                      \
    const u16* _s = KgA + (size_t)(ktn) * 128 * D_MODEL;                    \
    gload_lds16(_s, &sbuf[bn][0] + w * 512);                                \
    gload_lds16(_s + (size_t)64 * D_MODEL, &sbuf[bn][4096] + w * 512);      \
  } while (0)
#define SV1(bn, ktn)                                                        \
  do {                                                                      \
    const u16* _s = VgA + (size_t)(ktn) * 128;                              \
    gload_lds16(_s, &sbuf[bn][8192] + w * 512);                             \
    gload_lds16(_s + (size_t)32 * S_LEN, &sbuf[bn][12288] + w * 512);       \
  } while (0)

  // ================= pass 0: row sums (KBLK=256, 8 tiles) =================
  float lsA = 0.f, lsB = 0.f;

#define P0_BODY(BN, M0, M1)                                                 \
  {                                                                         \
    const u16* kc = &sbuf[BN][0];                                           \
    _Pragma("unroll") for (int t = 0; t < 16; t++) {                        \
      const u16* kr = kc + (t * 16 + lr) * 64;                              \
      bf16x8 k0 = *(const bf16x8*)(kr + ((lg ^ sw) << 3));                  \
      bf16x8 k1 = *(const bf16x8*)(kr + (((lg + 4) ^ sw) << 3));            \
      f32x4 a = {0.f, 0.f, 0.f, 0.f};                                       \
      a = MFMA16(k0, qf0, a);                                               \
      a = MFMA16(k1, qf1, a);                                               \
      u32 wbits = (t >> 1) == 0 ? (M0).x                                    \
                : (t >> 1) == 1 ? (M0).y                                    \
                : (t >> 1) == 2 ? (M0).z                                    \
                : (t >> 1) == 3 ? (M0).w                                    \
                : (t >> 1) == 4 ? (M1).x                                    \
                : (t >> 1) == 5 ? (M1).y                                    \
                : (t >> 1) == 6 ? (M1).z : (M1).w;                          \
      _Pragma("unroll") for (int r = 0; r < 4; r++) {                       \
        int j = (t * 16 + lg * 4 + r) & 31;                                 \
        float s = ((wbits >> j) & 1u) ? NEGV : a[r];                        \
        if (r & 1) lsB += exp2f(s); else lsA += exp2f(s);                   \
      }                                                                     \
    }                                                                       \
  }

  uint4 mA0, mA1, mB0, mB1;
  mA0 = *(const uint4*)(mrow);
  mA1 = *(const uint4*)(mrow + 4);
  SK0(0, 0);
  // tiles j = 0..5 (3 double-iterations), then 6, 7 peeled
  for (int jt = 0; jt < 3; jt++) {
    int j = jt * 2;
    mB0 = *(const uint4*)(mrow + (j + 1) * 8);
    mB1 = *(const uint4*)(mrow + (j + 1) * 8 + 4);
    SK0(1, j + 1);
    WAITCNT(4);  // leave <=4 newest (gloads of group j+1); retires all of group j
    BAR();
    P0_BODY(0, mA0, mA1);
    BAR();
    mA0 = *(const uint4*)(mrow + (j + 2) * 8);
    mA1 = *(const uint4*)(mrow + (j + 2) * 8 + 4);
    SK0(0, j + 2);
    WAITCNT(4);
    BAR();
    P0_BODY(1, mB0, mB1);
    BAR();
  }
  // j = 6 (stages tile 7)
  mB0 = *(const uint4*)(mrow + 7 * 8);
  mB1 = *(const uint4*)(mrow + 7 * 8 + 4);
  SK0(1, 7);
  WAITCNT(4);
  BAR();
  P0_BODY(0, mA0, mA1);
  BAR();
  // j = 7
  WAITCNT(0);
  BAR();
  P0_BODY(1, mB0, mB1);

  float lsum = lsA + lsB;
  lsum += __shfl_xor(lsum, 16);
  lsum += __shfl_xor(lsum, 32);
  float il2 = lsum > 0.f ? -__log2f(lsum) : 0.f;  // fold 1/lsum into exponent

  BAR();  // seal pass-0 buf reads before pass-1 staging overwrites

  // ================= pass 1: write attn, PV accumulate (KVBLK=128, r8) =============
  f32x4 ctxacc[4] = {};
  uint4 mA, mB;

#if defined(HAVE_MFMA_16x16x16)
#define P1_BODY(BN, MM, KT)                                                 \
  {                                                                         \
    const u16* kc = &sbuf[BN][0];                                           \
    const u16* vc = &sbuf[BN][8192];                                        \
    _Pragma("unroll") for (int t = 0; t < 8; t++) {                         \
      const u16* kr = kc + (t * 16 + lr) * 64;                              \
      bf16x8 k0 = *(const bf16x8*)(kr + ((lg ^ sw) << 3));                  \
      bf16x8 k1 = *(const bf16x8*)(kr + (((lg + 4) ^ sw) << 3));            \
      f32x4 a = {0.f, 0.f, 0.f, 0.f};                                       \
      a = MFMA16(k0, qf0, a);                                                \
      a = MFMA16(k1, qf1, a);                                                \
      u32 wbits = (t >> 1) == 0 ? (MM).x                                    \
                : (t >> 1) == 1 ? (MM).y                                    \
                : (t >> 1) == 2 ? (MM).z : (MM).w;                          \
      f32x4 p;                                                              \
      u16x4 pb;                                                             \
      _Pragma("unroll") for (int r = 0; r < 4; r++) {                       \
        int j = (t * 16 + lg * 4 + r) & 31;                                 \
        float s = ((wbits >> j) & 1u) ? NEGV : (a[r] + il2);                \
        float pv = exp2f(s);                                                \
        p[r] = pv;                                                          \
        pb[r] = f2bf(pv);                                                   \
      }                                                                     \
      *(f32x4*)(attn_b + (KT) * 128 + t * 16 + lg * 4) = p;                 \
      s16x4 ap = {(short)pb[0], (short)pb[1], (short)pb[2], (short)pb[3]};  \
      _Pragma("unroll") for (int d = 0; d < 4; d++) {                       \
        s16x4 vf = *(const s16x4*)(vc + (d * 16 + lr) * 128 +               \
                                   (((t * 2 + (lg >> 1)) ^ sw) << 3) +      \
                                   ((lg & 1) << 2));                        \
        ctxacc[d] = MFMA_PV(ap, vf, ctxacc[d]);                             \
      }                                                                     \
    }                                                                       \
  }
#else
#define P1_BODY(BN, MM, KT)                                                 \
  {                                                                         \
    const u16* kc = &sbuf[BN][0];                                           \
    const u16* vc = &sbuf[BN][8192];                                        \
    u16* pw = &pbuf[w][0];                                                  \
    _Pragma("unroll") for (int h2 = 0; h2 < 2; h2++) {                      \
      _Pragma("unroll") for (int tt = 0; tt < 4; tt++) {                    \
        const int t = h2 * 4 + tt;                                          \
        const u16* kr = kc + (t * 16 + lr) * 64;                            \
        bf16x8 k0 = *(const bf16x8*)(kr + ((lg ^ sw) << 3));                \
        bf16x8 k1 = *(const bf16x8*)(kr + (((lg + 4) ^ sw) << 3));          \
        f32x4 a = {0.f, 0.f, 0.f, 0.f};                                     \
        a = MFMA16(k0, qf0, a);                                              \
        a = MFMA16(k1, qf1, a);                                              \
        u32 wbits = (t >> 1) == 0 ? (MM).x                                  \
                  : (t >> 1) == 1 ? (MM).y                                  \
                  : (t >> 1) == 2 ? (MM).z : (MM).w;                        \
        f32x4 p;                                                            \
        u16x4 pb;                                                           \
        _Pragma("unroll") for (int r = 0; r < 4; r++) {                     \
          int j = (t * 16 + lg * 4 + r) & 31;                               \
          float s = ((wbits >> j) & 1u) ? NEGV : (a[r] + il2);              \
          float pv = exp2f(s);                                              \
          p[r] = pv;                                                        \
          pb[r] = f2bf(pv);                                                 \
        }                                                                   \
        *(f32x4*)(attn_b + (KT) * 128 + t * 16 + lg * 4) = p;               \
        *(u16x4*)(pw + lr * 64 + (((tt * 2 + (lg >> 1)) ^ sw) << 3) +       \
                  ((lg & 1) << 2)) = pb;                                    \
      }                                                                     \
      bf16x8 pa0 = *(const bf16x8*)(pw + lr * 64 + ((lg ^ sw) << 3));       \
      bf16x8 pa1 = *(const bf16x8*)(pw + lr * 64 + (((lg + 4) ^ sw) << 3)); \
      _Pragma("unroll") for (int d = 0; d < 4; d++) {                       \
        const u16* vr = vc + (d * 16 + lr) * 128 + (h2 << 6);               \
        bf16x8 v0 = *(const bf16x8*)(vr + ((lg ^ sw) << 3));                \
        bf16x8 v1 = *(const bf16x8*)(vr + (((lg + 4) ^ sw) << 3));          \
        ctxacc[d] = MFMA16(pa0, v0, ctxacc[d]);                             \
        ctxacc[d] = MFMA16(pa1, v1, ctxacc[d]);                             \
      }                                                                     \
    }                                                                       \
  }
#endif

  // r8 ledger (robust): WAITCNT(5) leaves only the newest 5-op group in flight and
  // retires EVERYTHING older (incl. however many store ops the compiler emitted).
  mA = *(const uint4*)(mrow);
  SK1(0, 0);
  SV1(0, 0);
  for (int it = 0; it < 7; it++) {
    int kt = it * 2;
    mB = *(const uint4*)(mrow + (kt + 1) * 4);
    SK1(1, kt + 1);
    SV1(1, kt + 1);
    WAITCNT(5);
    BAR();
    P1_BODY(0, mA, kt);
    BAR();
    mA = *(const uint4*)(mrow + (kt + 2) * 4);
    SK1(0, kt + 2);
    SV1(0, kt + 2);
    WAITCNT(5);
    BAR();
    P1_BODY(1, mB, kt + 1);
    BAR();
  }
  // kt = 14 (stages tile 15)
  mB = *(const uint4*)(mrow + 15 * 4);
  SK1(1, 15);
  SV1(1, 15);
  WAITCNT(5);
  BAR();
  P1_BODY(0, mA, 14);
  BAR();
  // kt = 15: retire stage15+mask15 (oldest); leave prev tile's stores in flight
  WAITCNT(8);
  BAR();
  P1_BODY(1, mB, 15);

  // context out: [B,S,H,DH] == [M_TOK, D_MODEL] row-major
#pragma unroll
  for (int d = 0; d < 4; d++)
#pragma unroll
    for (int r = 0; r < 4; r++) {
      int sq = q0 + w * 16 + lg * 4 + r;
      ctx[(size_t)(b * S_LEN + sq) * D_MODEL + h * D_HEAD + d * 16 + lr] = f2bf(ctxacc[d][r]);
    }
#undef SK0
#undef SK1
#undef SV1
#undef P0_BODY
#undef P1_BODY
}

// ---------------- workspace layout (u16 units) ----------------
#define O_KBF 0u          // bf16 key input; reused for packed mask after projections
#define O_VBF 4194304u
#define O_QBF 8388608u
#define O_WQ 12582912u
#define O_WK 13631488u
#define O_WV 14680064u
#define O_WO 15728640u
#define O_QUP 16777216u
#define O_KUP 20971520u
#define O_VUP 25165824u   // V head-transposed [b][h][dh][s]
#define O_CTX 29360128u
// total = 33554432 u16 = 64 MiB

extern "C" void kernel_launch(void* const* d_in, const int* in_sizes, int n_in,
                              void* d_out, int out_size, void* d_ws, size_t ws_size,
                              hipStream_t stream) {
  const float* key = (const float*)d_in[0];
  const float* value = (const float*)d_in[1];
  const float* query = (const float*)d_in[2];
  const int* mask = (const int*)d_in[3];
  const float* Wq = (const float*)d_in[4];
  const float* bq = (const float*)d_in[5];
  const float* Wk = (const float*)d_in[6];
  const float* bk = (const float*)d_in[7];
  const float* Wv = (const float*)d_in[8];
  const float* bv = (const float*)d_in[9];
  const float* Wo = (const float*)d_in[10];
  const float* bo = (const float*)d_in[11];

  u16* ws = (u16*)d_ws;
  u16* kbf = ws + O_KBF;
  u16* vbf = ws + O_VBF;
  u16* qbf = ws + O_QBF;
  u16* wqb = ws + O_WQ;
  u16* wkb = ws + O_WK;
  u16* wvb = ws + O_WV;
  u16* wob = ws + O_WO;
  u16* qup = ws + O_QUP;
  u16* kup = ws + O_KUP;
  u16* vtg = ws + O_VUP;
  u16* ctxb = ws + O_CTX;

  float* out = (float*)d_out;
  float* attn = out + (size_t)N_BATCH * S_LEN * D_MODEL;

  cvt7_kernel<<<dim3(512, 7), 256, 0, stream>>>(key, value, query, Wq, Wk, Wv, Wo, kbf, vbf, qbf,
                                                wqb, wkb, wvb, wob);
  proj3_kernel<<<dim3(32, 8, 3), 256, 0, stream>>>(kbf, vbf, qbf, wkb, wvb, wqb, bk, bv, bq, kup,
                                                   vtg, qup);
  pack_mask<<<1024, 256, 0, stream>>>(mask, (u64*)kbf);
  attn_kernel<<<512, 512, 0, stream>>>(qup, kup, vtg, (const u32*)kbf, attn, ctxb);
  gemm_out_kernel<<<dim3(32, 8), 256, 0, stream>>>(ctxb, wob, bo, out);
}